// Round 4
// baseline (319.674 us; speedup 1.0000x reference)
//
#include <hip/hip_runtime.h>
#include <cstddef>
#include <cstdint>

#define CH 512
#define SEQ 1024
#define NH 8
#define HD 64

typedef unsigned short u16;
typedef __attribute__((ext_vector_type(8))) short bf16x8;   // 8 bf16 (4 VGPRs), guide §3 form
typedef __attribute__((ext_vector_type(4))) float f32x4;
typedef __attribute__((ext_vector_type(4))) unsigned short u16x4;

__device__ __forceinline__ u16 f2bf(float f) {
  unsigned u = __float_as_uint(f);
  u += 0x7fffu + ((u >> 16) & 1u);
  return (u16)(u >> 16);
}
__device__ __forceinline__ float bf2f(u16 h) {
  return __uint_as_float(((unsigned)h) << 16);
}

__device__ __forceinline__ void gld16(void* lds, const void* g) {
  __builtin_amdgcn_global_load_lds(
      (const __attribute__((address_space(1))) unsigned int*)g,
      (__attribute__((address_space(3))) unsigned int*)lds, 16, 0, 0);
}

__device__ __forceinline__ f32x4 mfma16(bf16x8 a, bf16x8 b, f32x4 c) {
  return __builtin_amdgcn_mfma_f32_16x16x32_bf16(a, b, c, 0, 0, 0);
}

// ---------------- split: fp32 -> bf16 hi + lo ----------------
__global__ __launch_bounds__(256) void split_plain(
    const float* __restrict__ in, u16* __restrict__ hi, u16* __restrict__ lo, int n4)
{
  int i = blockIdx.x * 256 + threadIdx.x;
  if (i < n4) {
    float4 v = ((const float4*)in)[i];
    float vv0 = v.x, vv1 = v.y, vv2 = v.z, vv3 = v.w;
    u16x4 h, l;
    h[0] = f2bf(vv0); l[0] = f2bf(vv0 - bf2f(h[0]));
    h[1] = f2bf(vv1); l[1] = f2bf(vv1 - bf2f(h[1]));
    h[2] = f2bf(vv2); l[2] = f2bf(vv2 - bf2f(h[2]));
    h[3] = f2bf(vv3); l[3] = f2bf(vv3 - bf2f(h[3]));
    ((u16x4*)hi)[i] = h;
    ((u16x4*)lo)[i] = l;
  }
}

// x (b, 512 c, 1024 s) fp32 -> xt_hi/lo (b, 1024 s, 512 c) bf16
__global__ __launch_bounds__(256) void transpose_split(
    const float* __restrict__ x, u16* __restrict__ xh, u16* __restrict__ xl)
{
  __shared__ float tile[64][65];
  const int s0 = blockIdx.x * 64, c0 = blockIdx.y * 64, bz = blockIdx.z;
  const int t = threadIdx.x;
  #pragma unroll
  for (int p = 0; p < 16; ++p) {
    int i = p * 256 + t;
    int cl = i >> 6, sl = i & 63;
    tile[cl][sl] = x[((size_t)bz * CH + c0 + cl) * SEQ + s0 + sl];
  }
  __syncthreads();
  #pragma unroll
  for (int p = 0; p < 16; ++p) {
    int i = p * 256 + t;
    int sl = i >> 6, cl = i & 63;
    float v = tile[cl][sl];
    u16 h = f2bf(v);
    size_t idx = ((size_t)bz * SEQ + s0 + sl) * CH + c0 + cl;
    xh[idx] = h;
    xl[idx] = f2bf(v - bf2f(h));
  }
}

// ---------------- hi/lo split-bf16 GEMM ----------------
// C(bz) = A(MxK=512) * BT(bz, N=1024, K=512)^T + bias
// MODE 0: o0 = fp32 out (b, 512, 1024)
// MODE 1: qkv epilogue -> o0..o4 = q_hi,q_lo,k_hi,k_lo,v_hi
template<int MODE>
__global__ __launch_bounds__(256, 2) void gemm_hilo(
    const u16* __restrict__ Ah, const u16* __restrict__ Al,
    const u16* __restrict__ BTh, const u16* __restrict__ BTl,
    const float* __restrict__ bias,
    void* __restrict__ o0, void* __restrict__ o1, void* __restrict__ o2,
    void* __restrict__ o3, void* __restrict__ o4)
{
  const int bx = blockIdx.x, by = blockIdx.y, bz = blockIdx.z;
  const int m0 = by * 128, n0 = bx * 128;
  const char* Ahc = (const char*)Ah;
  const char* Alc = (const char*)Al;
  const char* Bhc = (const char*)BTh + (size_t)bz * SEQ * CH * 2;
  const char* Blc = (const char*)BTl + (size_t)bz * SEQ * CH * 2;

  // rows of 128B: [32 bf16 hi | 32 bf16 lo], XOR-swizzled by (row&7)<<4
  __shared__ __align__(16) u16 As[128 * 64];
  __shared__ __align__(16) u16 Bs[128 * 64];

  const int t = threadIdx.x, w = t >> 6, lane = t & 63;
  const int lr = lane & 15, lg = lane >> 4;
  const int wr = w >> 1, wc = w & 1;

  f32x4 acc[4][4];
  #pragma unroll
  for (int i = 0; i < 4; ++i)
    #pragma unroll
    for (int j = 0; j < 4; ++j) acc[i][j] = (f32x4){0.f, 0.f, 0.f, 0.f};

  for (int k0 = 0; k0 < CH; k0 += 32) {
    __syncthreads();
    #pragma unroll
    for (int p = 0; p < 4; ++p) {
      const int ldsoff = p * 4096 + w * 1024 + lane * 16;
      const int m = ldsoff >> 7;
      const int W = ldsoff & 127;
      const int Wp = W ^ ((m & 7) << 4);
      const char* src = (Wp < 64 ? Ahc : Alc) + ((size_t)(m0 + m) * CH + k0) * 2 + (Wp & 63);
      gld16((char*)As + p * 4096 + w * 1024, src);
    }
    #pragma unroll
    for (int p = 0; p < 4; ++p) {
      const int ldsoff = p * 4096 + w * 1024 + lane * 16;
      const int n = ldsoff >> 7;
      const int W = ldsoff & 127;
      const int Wp = W ^ ((n & 7) << 4);
      const char* src = (Wp < 64 ? Bhc : Blc) + ((size_t)(n0 + n) * CH + k0) * 2 + (Wp & 63);
      gld16((char*)Bs + p * 4096 + w * 1024, src);
    }
    __syncthreads();

    bf16x8 Afh[4], Afl[4], Bfh[4], Bfl[4];
    #pragma unroll
    for (int mi = 0; mi < 4; ++mi) {
      const int m = wr * 64 + mi * 16 + lr;
      const int swz = (m & 7) << 4;
      Afh[mi] = *(const bf16x8*)((const char*)As + m * 128 + ((lg * 16) ^ swz));
      Afl[mi] = *(const bf16x8*)((const char*)As + m * 128 + ((64 + lg * 16) ^ swz));
    }
    #pragma unroll
    for (int ni = 0; ni < 4; ++ni) {
      const int n = wc * 64 + ni * 16 + lr;
      const int swz = (n & 7) << 4;
      Bfh[ni] = *(const bf16x8*)((const char*)Bs + n * 128 + ((lg * 16) ^ swz));
      Bfl[ni] = *(const bf16x8*)((const char*)Bs + n * 128 + ((64 + lg * 16) ^ swz));
    }
    #pragma unroll
    for (int mi = 0; mi < 4; ++mi) {
      #pragma unroll
      for (int ni = 0; ni < 4; ++ni) {
        acc[mi][ni] = mfma16(Afh[mi], Bfh[ni], acc[mi][ni]);
        acc[mi][ni] = mfma16(Afh[mi], Bfl[ni], acc[mi][ni]);
        acc[mi][ni] = mfma16(Afl[mi], Bfh[ni], acc[mi][ni]);
      }
    }
  }

  if constexpr (MODE == 0) {
    float* Out = (float*)o0 + (size_t)bz * CH * SEQ;
    #pragma unroll
    for (int mi = 0; mi < 4; ++mi) {
      const int mb = m0 + wr * 64 + mi * 16 + lg * 4;
      #pragma unroll
      for (int r = 0; r < 4; ++r) {
        const float bv = bias[mb + r];
        #pragma unroll
        for (int ni = 0; ni < 4; ++ni) {
          const int n = n0 + wc * 64 + ni * 16 + lr;
          Out[(size_t)(mb + r) * SEQ + n] = acc[mi][ni][r] + bv;
        }
      }
    }
  } else {
    u16* qh = (u16*)o0; u16* ql = (u16*)o1;
    u16* kh = (u16*)o2; u16* kl = (u16*)o3;
    u16* vh = (u16*)o4;
    #pragma unroll
    for (int mi = 0; mi < 4; ++mi) {
      const int mb = m0 + wr * 64 + mi * 16 + lg * 4;   // 4 consecutive m rows
      const int sec = mb >> 9;                          // 0=q 1=k 2=v
      const int h = (mb >> 6) & 7;
      const int d = mb & 63;
      const size_t bh = (size_t)bz * NH + h;
      const float b0 = bias[mb + 0], b1 = bias[mb + 1], b2 = bias[mb + 2], b3 = bias[mb + 3];
      #pragma unroll
      for (int ni = 0; ni < 4; ++ni) {
        const int n = n0 + wc * 64 + ni * 16 + lr;      // s
        const float c0 = acc[mi][ni][0] + b0;
        const float c1 = acc[mi][ni][1] + b1;
        const float c2 = acc[mi][ni][2] + b2;
        const float c3 = acc[mi][ni][3] + b3;
        if (sec == 2) {
          u16* dst = vh + (bh * HD + d) * SEQ + n;      // v transposed (b,h,d,s)
          dst[0 * SEQ] = f2bf(c0);
          dst[1 * SEQ] = f2bf(c1);
          dst[2 * SEQ] = f2bf(c2);
          dst[3 * SEQ] = f2bf(c3);
        } else {
          u16* dsth = (sec == 0 ? qh : kh) + (bh * SEQ + n) * HD + d;
          u16* dstl = (sec == 0 ? ql : kl) + (bh * SEQ + n) * HD + d;
          u16x4 hv, lv;
          hv[0] = f2bf(c0); lv[0] = f2bf(c0 - bf2f(hv[0]));
          hv[1] = f2bf(c1); lv[1] = f2bf(c1 - bf2f(hv[1]));
          hv[2] = f2bf(c2); lv[2] = f2bf(c2 - bf2f(hv[2]));
          hv[3] = f2bf(c3); lv[3] = f2bf(c3 - bf2f(hv[3]));
          *(u16x4*)dsth = hv;
          *(u16x4*)dstl = lv;
        }
      }
    }
  }
}

// ---------------- flash attention, MFMA, barrier-free ----------------
// q,k: (b,h,1024,64) hi/lo bf16; v: (b,h,64,1024) bf16; out avt: (b,1024,512) hi/lo
// K/V are L2-resident (384 KB/head): read MFMA fragments DIRECTLY from global,
// no LDS staging, no __syncthreads in the kt loop (m169: staging L2-fit data
// is pure overhead). P stays in wave-local LDS (no cross-wave sharing).
__global__ __launch_bounds__(256, 2) void attn_mfma(
    const u16* __restrict__ q_h, const u16* __restrict__ q_l,
    const u16* __restrict__ k_h, const u16* __restrict__ k_l,
    const u16* __restrict__ v_h,
    u16* __restrict__ av_h, u16* __restrict__ av_l)
{
  const int qt = blockIdx.x, hh = blockIdx.y, bz = blockIdx.z;
  const int bhead = bz * NH + hh;
  const int s0 = qt * 64;
  const int t = threadIdx.x, w = t >> 6, lane = t & 63;
  const int lr = lane & 15, lg = lane >> 4;

  __shared__ __align__(16) u16 Ps_s[4 * 16 * 64]; // per-wave [qi][kj], swizzled

  // Q fragments in registers (wave w owns q-rows s0 + w*16 .. +16)
  bf16x8 QAh[2], QAl[2];
  {
    const size_t qrow = (size_t)bhead * SEQ + s0 + w * 16 + lr;
    #pragma unroll
    for (int ks = 0; ks < 2; ++ks) {
      QAh[ks] = *(const bf16x8*)((const char*)q_h + qrow * 128 + ks * 64 + lg * 16);
      QAl[ks] = *(const bf16x8*)((const char*)q_l + qrow * 128 + ks * 64 + lg * 16);
    }
  }

  // per-head bases
  const char* Khb = (const char*)k_h + (size_t)bhead * SEQ * 128;
  const char* Klb = (const char*)k_l + (size_t)bhead * SEQ * 128;
  const char* Vbb = (const char*)v_h + (size_t)bhead * HD * 2048;

  // exp2 domain: S2 = S * 0.125 * log2(e); softmax invariant under the scaling
  const float SCL = 0.1803368801111204f;

  float mrow[4], lsum[4];
  f32x4 oacc[4];
  #pragma unroll
  for (int r = 0; r < 4; ++r) { mrow[r] = -1e30f; lsum[r] = 0.f; }
  #pragma unroll
  for (int ni = 0; ni < 4; ++ni) oacc[ni] = (f32x4){0.f, 0.f, 0.f, 0.f};

  for (int kt = 0; kt < 16; ++kt) {
    // ---- S = Q K^T, fragments straight from global (L2-hit) ----
    f32x4 sc[4];
    #pragma unroll
    for (int ni = 0; ni < 4; ++ni) sc[ni] = (f32x4){0.f, 0.f, 0.f, 0.f};
    #pragma unroll
    for (int ks = 0; ks < 2; ++ks) {
      bf16x8 kbh[4], kbl[4];
      #pragma unroll
      for (int ni = 0; ni < 4; ++ni) {
        const int kj = kt * 64 + ni * 16 + lr;
        kbh[ni] = *(const bf16x8*)(Khb + (size_t)kj * 128 + ks * 64 + lg * 16);
        kbl[ni] = *(const bf16x8*)(Klb + (size_t)kj * 128 + ks * 64 + lg * 16);
      }
      __builtin_amdgcn_s_setprio(1);
      #pragma unroll
      for (int ni = 0; ni < 4; ++ni) {
        sc[ni] = mfma16(QAh[ks], kbh[ni], sc[ni]);
        sc[ni] = mfma16(QAh[ks], kbl[ni], sc[ni]);
        sc[ni] = mfma16(QAl[ks], kbh[ni], sc[ni]);
      }
      __builtin_amdgcn_s_setprio(0);
    }
    #pragma unroll
    for (int ni = 0; ni < 4; ++ni)
      #pragma unroll
      for (int r = 0; r < 4; ++r) sc[ni][r] *= SCL;

    // ---- online softmax (row = lg*4+r; 64 cols live on 16 lr-lanes x 4 frags)
    float tm[4], rs[4], al[4];
    #pragma unroll
    for (int r = 0; r < 4; ++r)
      tm[r] = fmaxf(fmaxf(sc[0][r], sc[1][r]), fmaxf(sc[2][r], sc[3][r]));
    #pragma unroll
    for (int off = 1; off < 16; off <<= 1) {
      #pragma unroll
      for (int r = 0; r < 4; ++r) tm[r] = fmaxf(tm[r], __shfl_xor(tm[r], off));
    }
    #pragma unroll
    for (int r = 0; r < 4; ++r) {
      const float mn = fmaxf(mrow[r], tm[r]);
      al[r] = exp2f(mrow[r] - mn);
      mrow[r] = mn;
      rs[r] = 0.f;
    }
    #pragma unroll
    for (int ni = 0; ni < 4; ++ni) {
      #pragma unroll
      for (int r = 0; r < 4; ++r) {
        const float pf = exp2f(sc[ni][r] - mrow[r]);
        rs[r] += pf;
        const int qi = lg * 4 + r;
        const int col = ni * 16 + lr;
        *(u16*)((char*)Ps_s + w * 2048 + qi * 128 + ((col * 2) ^ ((qi & 7) << 4))) = f2bf(pf);
      }
    }
    #pragma unroll
    for (int off = 1; off < 16; off <<= 1) {
      #pragma unroll
      for (int r = 0; r < 4; ++r) rs[r] += __shfl_xor(rs[r], off);
    }
    #pragma unroll
    for (int r = 0; r < 4; ++r) lsum[r] = lsum[r] * al[r] + rs[r];
    #pragma unroll
    for (int ni = 0; ni < 4; ++ni)
      #pragma unroll
      for (int r = 0; r < 4; ++r) oacc[ni][r] *= al[r];

    // ---- O += P V   (P wave-local in LDS; V fragments from global) ----
    #pragma unroll
    for (int ks = 0; ks < 2; ++ks) {
      const int off0 = ks * 64 + lg * 16;
      bf16x8 pa = *(const bf16x8*)((const char*)Ps_s + w * 2048 + lr * 128 + (off0 ^ ((lr & 7) << 4)));
      bf16x8 vb[4];
      #pragma unroll
      for (int ni = 0; ni < 4; ++ni) {
        const int d = ni * 16 + lr;
        vb[ni] = *(const bf16x8*)(Vbb + (size_t)d * 2048 + kt * 128 + ks * 64 + lg * 16);
      }
      __builtin_amdgcn_s_setprio(1);
      #pragma unroll
      for (int ni = 0; ni < 4; ++ni) oacc[ni] = mfma16(pa, vb[ni], oacc[ni]);
      __builtin_amdgcn_s_setprio(0);
    }
  }

  // write avt (b, s, c) hi/lo
  #pragma unroll
  for (int r = 0; r < 4; ++r) {
    const float inv = 1.f / lsum[r];
    const int s = s0 + w * 16 + lg * 4 + r;
    #pragma unroll
    for (int ni = 0; ni < 4; ++ni) {
      const int c = hh * HD + ni * 16 + lr;
      const size_t idx = ((size_t)bz * SEQ + s) * CH + c;
      const float v = oacc[ni][r] * inv;
      const u16 hb = f2bf(v);
      av_h[idx] = hb;
      av_l[idx] = f2bf(v - bf2f(hb));
    }
  }
}

extern "C" void kernel_launch(void* const* d_in, const int* in_sizes, int n_in,
                              void* d_out, int out_size, void* d_ws, size_t ws_size,
                              hipStream_t stream) {
  const float* x     = (const float*)d_in[0];  // (8, 512, 32, 32)
  const float* w_qkv = (const float*)d_in[1];  // (1536, 512)
  const float* b_qkv = (const float*)d_in[2];  // (1536,)
  const float* w_o   = (const float*)d_in[3];  // (512, 512)
  const float* b_o   = (const float*)d_in[4];  // (512,)
  float* out = (float*)d_out;                  // (8, 512, 1024) fp32

  char* ws = (char*)d_ws;
  const size_t SZ = (size_t)8 * SEQ * CH * 2;  // one bf16 plane: 8.39 MB
  u16* xt_h = (u16*)(ws + 0 * SZ);             // also avt_h (aliased; xt dead after gemm1)
  u16* xt_l = (u16*)(ws + 1 * SZ);             // also avt_l
  u16* q_h  = (u16*)(ws + 2 * SZ);
  u16* q_l  = (u16*)(ws + 3 * SZ);
  u16* k_h  = (u16*)(ws + 4 * SZ);
  u16* k_l  = (u16*)(ws + 5 * SZ);
  u16* v_h  = (u16*)(ws + 6 * SZ);
  u16* wqkv_h = (u16*)(ws + 7 * SZ);
  u16* wqkv_l = wqkv_h + (size_t)1536 * 512;
  u16* wo_h   = wqkv_l + (size_t)1536 * 512;
  u16* wo_l   = wo_h + (size_t)512 * 512;

  split_plain<<<768, 256, 0, stream>>>(w_qkv, wqkv_h, wqkv_l, (1536 * 512) / 4);
  split_plain<<<256, 256, 0, stream>>>(w_o, wo_h, wo_l, (512 * 512) / 4);
  transpose_split<<<dim3(16, 8, 8), 256, 0, stream>>>(x, xt_h, xt_l);

  gemm_hilo<1><<<dim3(8, 12, 8), 256, 0, stream>>>(
      wqkv_h, wqkv_l, xt_h, xt_l, b_qkv,
      (void*)q_h, (void*)q_l, (void*)k_h, (void*)k_l, (void*)v_h);

  attn_mfma<<<dim3(16, 8, 8), 256, 0, stream>>>(
      q_h, q_l, k_h, k_l, v_h, xt_h, xt_l);   // avt aliases xt

  gemm_hilo<0><<<dim3(8, 4, 8), 256, 0, stream>>>(
      wo_h, wo_l, xt_h, xt_l, b_o,
      (void*)out, nullptr, nullptr, nullptr, nullptr);
}

// Round 5
// 241.288 us; speedup vs baseline: 1.3249x; 1.3249x over previous
//
#include <hip/hip_runtime.h>
#include <cstddef>
#include <cstdint>

#define CH 512
#define SEQ 1024
#define NH 8
#define HD 64

typedef unsigned short u16;
typedef unsigned int u32;
typedef __attribute__((ext_vector_type(8))) short bf16x8;   // 8 bf16 (4 VGPRs), guide §3 form
typedef __attribute__((ext_vector_type(4))) float f32x4;
typedef __attribute__((ext_vector_type(4))) unsigned short u16x4;

// 0.125 * log2(e): folds the 1/sqrt(64) score scale and exp->exp2 conversion
#define SCLQ 0.1803368801111204f

__device__ __forceinline__ u16 f2bf(float f) {
  unsigned u = __float_as_uint(f);
  u += 0x7fffu + ((u >> 16) & 1u);
  return (u16)(u >> 16);
}
__device__ __forceinline__ float bf2f(u16 h) {
  return __uint_as_float(((unsigned)h) << 16);
}
__device__ __forceinline__ u32 cvtpk(float lo, float hi) {
  u32 r;
  asm("v_cvt_pk_bf16_f32 %0, %1, %2" : "=v"(r) : "v"(lo), "v"(hi));
  return r;
}

__device__ __forceinline__ void gld16(void* lds, const void* g) {
  __builtin_amdgcn_global_load_lds(
      (const __attribute__((address_space(1))) unsigned int*)g,
      (__attribute__((address_space(3))) unsigned int*)lds, 16, 0, 0);
}

__device__ __forceinline__ f32x4 mfma16(bf16x8 a, bf16x8 b, f32x4 c) {
  return __builtin_amdgcn_mfma_f32_16x16x32_bf16(a, b, c, 0, 0, 0);
}

// ---------------- split: fp32 -> bf16 hi + lo ----------------
__global__ __launch_bounds__(256) void split_plain(
    const float* __restrict__ in, u16* __restrict__ hi, u16* __restrict__ lo, int n4)
{
  int i = blockIdx.x * 256 + threadIdx.x;
  if (i < n4) {
    float4 v = ((const float4*)in)[i];
    float vv0 = v.x, vv1 = v.y, vv2 = v.z, vv3 = v.w;
    u16x4 h, l;
    h[0] = f2bf(vv0); l[0] = f2bf(vv0 - bf2f(h[0]));
    h[1] = f2bf(vv1); l[1] = f2bf(vv1 - bf2f(h[1]));
    h[2] = f2bf(vv2); l[2] = f2bf(vv2 - bf2f(h[2]));
    h[3] = f2bf(vv3); l[3] = f2bf(vv3 - bf2f(h[3]));
    ((u16x4*)hi)[i] = h;
    ((u16x4*)lo)[i] = l;
  }
}

// x (b, 512 c, 1024 s) fp32 -> xt_hi/lo (b, 1024 s, 512 c) bf16
__global__ __launch_bounds__(256) void transpose_split(
    const float* __restrict__ x, u16* __restrict__ xh, u16* __restrict__ xl)
{
  __shared__ float tile[64][65];
  const int s0 = blockIdx.x * 64, c0 = blockIdx.y * 64, bz = blockIdx.z;
  const int t = threadIdx.x;
  #pragma unroll
  for (int p = 0; p < 16; ++p) {
    int i = p * 256 + t;
    int cl = i >> 6, sl = i & 63;
    tile[cl][sl] = x[((size_t)bz * CH + c0 + cl) * SEQ + s0 + sl];
  }
  __syncthreads();
  #pragma unroll
  for (int p = 0; p < 16; ++p) {
    int i = p * 256 + t;
    int sl = i >> 6, cl = i & 63;
    float v = tile[cl][sl];
    u16 h = f2bf(v);
    size_t idx = ((size_t)bz * SEQ + s0 + sl) * CH + c0 + cl;
    xh[idx] = h;
    xl[idx] = f2bf(v - bf2f(h));
  }
}

// ---------------- hi/lo split-bf16 GEMM ----------------
// C(bz) = A(MxK=512) * BT(bz, N=1024, K=512)^T + bias
// MODE 0: o0 = fp32 out (b, 512, 1024)
// MODE 1: qkv epilogue -> o0..o4 = q_hi,q_lo,k_hi,k_lo,v_hi (q pre-scaled by SCLQ)
template<int MODE>
__global__ __launch_bounds__(256, 2) void gemm_hilo(
    const u16* __restrict__ Ah, const u16* __restrict__ Al,
    const u16* __restrict__ BTh, const u16* __restrict__ BTl,
    const float* __restrict__ bias,
    void* __restrict__ o0, void* __restrict__ o1, void* __restrict__ o2,
    void* __restrict__ o3, void* __restrict__ o4)
{
  const int bx = blockIdx.x, by = blockIdx.y, bz = blockIdx.z;
  const int m0 = by * 128, n0 = bx * 128;
  const char* Ahc = (const char*)Ah;
  const char* Alc = (const char*)Al;
  const char* Bhc = (const char*)BTh + (size_t)bz * SEQ * CH * 2;
  const char* Blc = (const char*)BTl + (size_t)bz * SEQ * CH * 2;

  // rows of 128B: [32 bf16 hi | 32 bf16 lo], XOR-swizzled by (row&7)<<4
  __shared__ __align__(16) u16 As[128 * 64];
  __shared__ __align__(16) u16 Bs[128 * 64];

  const int t = threadIdx.x, w = t >> 6, lane = t & 63;
  const int lr = lane & 15, lg = lane >> 4;
  const int wr = w >> 1, wc = w & 1;

  f32x4 acc[4][4];
  #pragma unroll
  for (int i = 0; i < 4; ++i)
    #pragma unroll
    for (int j = 0; j < 4; ++j) acc[i][j] = (f32x4){0.f, 0.f, 0.f, 0.f};

  for (int k0 = 0; k0 < CH; k0 += 32) {
    __syncthreads();
    #pragma unroll
    for (int p = 0; p < 4; ++p) {
      const int ldsoff = p * 4096 + w * 1024 + lane * 16;
      const int m = ldsoff >> 7;
      const int W = ldsoff & 127;
      const int Wp = W ^ ((m & 7) << 4);
      const char* src = (Wp < 64 ? Ahc : Alc) + ((size_t)(m0 + m) * CH + k0) * 2 + (Wp & 63);
      gld16((char*)As + p * 4096 + w * 1024, src);
    }
    #pragma unroll
    for (int p = 0; p < 4; ++p) {
      const int ldsoff = p * 4096 + w * 1024 + lane * 16;
      const int n = ldsoff >> 7;
      const int W = ldsoff & 127;
      const int Wp = W ^ ((n & 7) << 4);
      const char* src = (Wp < 64 ? Bhc : Blc) + ((size_t)(n0 + n) * CH + k0) * 2 + (Wp & 63);
      gld16((char*)Bs + p * 4096 + w * 1024, src);
    }
    __syncthreads();

    bf16x8 Afh[4], Afl[4], Bfh[4], Bfl[4];
    #pragma unroll
    for (int mi = 0; mi < 4; ++mi) {
      const int m = wr * 64 + mi * 16 + lr;
      const int swz = (m & 7) << 4;
      Afh[mi] = *(const bf16x8*)((const char*)As + m * 128 + ((lg * 16) ^ swz));
      Afl[mi] = *(const bf16x8*)((const char*)As + m * 128 + ((64 + lg * 16) ^ swz));
    }
    #pragma unroll
    for (int ni = 0; ni < 4; ++ni) {
      const int n = wc * 64 + ni * 16 + lr;
      const int swz = (n & 7) << 4;
      Bfh[ni] = *(const bf16x8*)((const char*)Bs + n * 128 + ((lg * 16) ^ swz));
      Bfl[ni] = *(const bf16x8*)((const char*)Bs + n * 128 + ((64 + lg * 16) ^ swz));
    }
    #pragma unroll
    for (int mi = 0; mi < 4; ++mi) {
      #pragma unroll
      for (int ni = 0; ni < 4; ++ni) {
        acc[mi][ni] = mfma16(Afh[mi], Bfh[ni], acc[mi][ni]);
        acc[mi][ni] = mfma16(Afh[mi], Bfl[ni], acc[mi][ni]);
        acc[mi][ni] = mfma16(Afl[mi], Bfh[ni], acc[mi][ni]);
      }
    }
  }

  if constexpr (MODE == 0) {
    float* Out = (float*)o0 + (size_t)bz * CH * SEQ;
    #pragma unroll
    for (int mi = 0; mi < 4; ++mi) {
      const int mb = m0 + wr * 64 + mi * 16 + lg * 4;
      #pragma unroll
      for (int r = 0; r < 4; ++r) {
        const float bv = bias[mb + r];
        #pragma unroll
        for (int ni = 0; ni < 4; ++ni) {
          const int n = n0 + wc * 64 + ni * 16 + lr;
          Out[(size_t)(mb + r) * SEQ + n] = acc[mi][ni][r] + bv;
        }
      }
    }
  } else {
    u16* qh = (u16*)o0; u16* ql = (u16*)o1;
    u16* kh = (u16*)o2; u16* kl = (u16*)o3;
    u16* vh = (u16*)o4;
    #pragma unroll
    for (int mi = 0; mi < 4; ++mi) {
      const int mb = m0 + wr * 64 + mi * 16 + lg * 4;   // 4 consecutive m rows
      const int sec = mb >> 9;                          // 0=q 1=k 2=v
      const int h = (mb >> 6) & 7;
      const int d = mb & 63;
      const size_t bh = (size_t)bz * NH + h;
      const float b0 = bias[mb + 0], b1 = bias[mb + 1], b2 = bias[mb + 2], b3 = bias[mb + 3];
      #pragma unroll
      for (int ni = 0; ni < 4; ++ni) {
        const int n = n0 + wc * 64 + ni * 16 + lr;      // s
        float c0 = acc[mi][ni][0] + b0;
        float c1 = acc[mi][ni][1] + b1;
        float c2 = acc[mi][ni][2] + b2;
        float c3 = acc[mi][ni][3] + b3;
        if (sec == 2) {
          u16* dst = vh + (bh * HD + d) * SEQ + n;      // v transposed (b,h,d,s)
          dst[0 * SEQ] = f2bf(c0);
          dst[1 * SEQ] = f2bf(c1);
          dst[2 * SEQ] = f2bf(c2);
          dst[3 * SEQ] = f2bf(c3);
        } else {
          if (sec == 0) { c0 *= SCLQ; c1 *= SCLQ; c2 *= SCLQ; c3 *= SCLQ; }
          u16* dsth = (sec == 0 ? qh : kh) + (bh * SEQ + n) * HD + d;
          u16* dstl = (sec == 0 ? ql : kl) + (bh * SEQ + n) * HD + d;
          u16x4 hv, lv;
          hv[0] = f2bf(c0); lv[0] = f2bf(c0 - bf2f(hv[0]));
          hv[1] = f2bf(c1); lv[1] = f2bf(c1 - bf2f(hv[1]));
          hv[2] = f2bf(c2); lv[2] = f2bf(c2 - bf2f(hv[2]));
          hv[3] = f2bf(c3); lv[3] = f2bf(c3 - bf2f(hv[3]));
          *(u16x4*)dsth = hv;
          *(u16x4*)dstl = lv;
        }
      }
    }
  }
}

// ---------------- flash attention, MFMA, swapped-QK + dbuf K + reg V ----------------
// q,k: (b,h,1024,64) hi/lo bf16 (q pre-scaled by SCLQ); v: (b,h,64,1024) bf16;
// out avt: (b,1024,512) hi/lo.
// Swapped QK^T: sc = mfma(K, Q) -> lane holds S[kj][qi=lr]; softmax row state is
// per-lane scalars (m, l); cross-lane only 2 shuffles for tile-max.
// K hi/lo double-buffered in LDS (1 barrier/tile, staging overlapped);
// V prefetched to registers at tile top (consumed after softmax).
__global__ __launch_bounds__(256, 2) void attn_mfma(
    const u16* __restrict__ q_h, const u16* __restrict__ q_l,
    const u16* __restrict__ k_h, const u16* __restrict__ k_l,
    const u16* __restrict__ v_h,
    u16* __restrict__ av_h, u16* __restrict__ av_l)
{
  const int qt = blockIdx.x, hh = blockIdx.y, bz = blockIdx.z;
  const int bhead = bz * NH + hh;
  const int s0 = qt * 64;
  const int t = threadIdx.x, w = t >> 6, lane = t & 63;
  const int lr = lane & 15, lg = lane >> 4;

  __shared__ __align__(16) u16 KsH[2][64 * 64];   // [buf][kj][d] swizzled, 8KB each
  __shared__ __align__(16) u16 KsL[2][64 * 64];
  __shared__ __align__(16) u16 Ps_s[4][16 * 64];  // per-wave [qi][kj] swizzled, 2KB each

  // Q B-fragments (q pre-scaled by SCLQ in gemm epilogue)
  bf16x8 QBh[2], QBl[2];
  {
    const size_t qrow = (size_t)bhead * SEQ + s0 + w * 16 + lr;
    #pragma unroll
    for (int ks = 0; ks < 2; ++ks) {
      QBh[ks] = *(const bf16x8*)((const char*)q_h + qrow * 128 + ks * 64 + lg * 16);
      QBl[ks] = *(const bf16x8*)((const char*)q_l + qrow * 128 + ks * 64 + lg * 16);
    }
  }

  const char* Khb = (const char*)k_h + (size_t)bhead * SEQ * 128;
  const char* Klb = (const char*)k_l + (size_t)bhead * SEQ * 128;
  const char* Vbb = (const char*)v_h + (size_t)bhead * HD * 2048;

  // stage K tile (hi+lo, 16KB) into buffer `buf`: 4 gld16/thread, coalesced,
  // source pre-swizzled so LDS is linear-dest (rule #21).
  auto STAGE = [&](int buf, int tile) {
    const char* khs = Khb + (size_t)tile * 64 * 128;
    const char* kls = Klb + (size_t)tile * 64 * 128;
    #pragma unroll
    for (int p = 0; p < 2; ++p) {
      const int ldsoff = p * 4096 + w * 1024 + lane * 16;
      const int r = ldsoff >> 7;
      const int Wp = (ldsoff & 127) ^ ((r & 7) << 4);
      gld16((char*)KsH[buf] + p * 4096 + w * 1024, khs + r * 128 + Wp);
      gld16((char*)KsL[buf] + p * 4096 + w * 1024, kls + r * 128 + Wp);
    }
  };

  float mreg = -1e30f, lreg = 0.f;   // per-lane row state (row qi = lr)
  f32x4 oacc[4];
  #pragma unroll
  for (int ni = 0; ni < 4; ++ni) oacc[ni] = (f32x4){0.f, 0.f, 0.f, 0.f};

  STAGE(0, 0);
  __syncthreads();

  for (int kt = 0; kt < 16; ++kt) {
    const int cur = kt & 1;

    // V prefetch to registers (oldest vmem ops -> PV's wait leaves staging in flight)
    bf16x8 vb[2][4];
    #pragma unroll
    for (int ks = 0; ks < 2; ++ks)
      #pragma unroll
      for (int ni = 0; ni < 4; ++ni) {
        const int d = ni * 16 + lr;
        vb[ks][ni] = *(const bf16x8*)(Vbb + (size_t)d * 2048 + kt * 128 + ks * 64 + lg * 16);
      }

    // stage next K tile into the other buffer (completes by end-of-tile barrier)
    if (kt < 15) STAGE(cur ^ 1, kt + 1);

    // ---- S^T = K Q^T (swapped): sc[ni][r] = S[kj = ni*16+lg*4+r][qi = lr] ----
    f32x4 sc[4];
    #pragma unroll
    for (int ni = 0; ni < 4; ++ni) sc[ni] = (f32x4){0.f, 0.f, 0.f, 0.f};
    #pragma unroll
    for (int ks = 0; ks < 2; ++ks) {
      bf16x8 kfh[4], kfl[4];
      #pragma unroll
      for (int ni = 0; ni < 4; ++ni) {
        const int row = ni * 16 + lr;
        const int off = (ks * 64 + lg * 16) ^ ((row & 7) << 4);
        kfh[ni] = *(const bf16x8*)((const char*)KsH[cur] + row * 128 + off);
        kfl[ni] = *(const bf16x8*)((const char*)KsL[cur] + row * 128 + off);
      }
      __builtin_amdgcn_s_setprio(1);
      #pragma unroll
      for (int ni = 0; ni < 4; ++ni) {
        sc[ni] = mfma16(kfh[ni], QBh[ks], sc[ni]);
        sc[ni] = mfma16(kfl[ni], QBh[ks], sc[ni]);
        sc[ni] = mfma16(kfh[ni], QBl[ks], sc[ni]);
      }
      __builtin_amdgcn_s_setprio(0);
    }

    // ---- per-lane online softmax (row qi = lr; 16 vals/lane, 4 lanes/row) ----
    float tm = fmaxf(fmaxf(sc[0][0], sc[0][1]), fmaxf(sc[0][2], sc[0][3]));
    #pragma unroll
    for (int ni = 1; ni < 4; ++ni)
      tm = fmaxf(tm, fmaxf(fmaxf(sc[ni][0], sc[ni][1]), fmaxf(sc[ni][2], sc[ni][3])));
    tm = fmaxf(tm, __shfl_xor(tm, 16));
    tm = fmaxf(tm, __shfl_xor(tm, 32));

    if (!__all(tm <= mreg + 8.0f)) {           // defer-max (T13): P bounded by 2^8
      const float mn = fmaxf(mreg, tm);
      const float alv = exp2f(mreg - mn);
      mreg = mn;
      lreg *= alv;
      float alr[4];
      #pragma unroll
      for (int r = 0; r < 4; ++r) alr[r] = __shfl(alv, lg * 4 + r);
      #pragma unroll
      for (int ni = 0; ni < 4; ++ni)
        #pragma unroll
        for (int r = 0; r < 4; ++r) oacc[ni][r] *= alr[r];
    }

    #pragma unroll
    for (int ni = 0; ni < 4; ++ni) {
      float pf[4];
      #pragma unroll
      for (int r = 0; r < 4; ++r) {
        pf[r] = exp2f(sc[ni][r] - mreg);
        lreg += pf[r];
      }
      const u32 p01 = cvtpk(pf[0], pf[1]);
      const u32 p23 = cvtpk(pf[2], pf[3]);
      // kj = ni*16 + lg*4 + {0..3} -> 8 contiguous bytes in row lr
      *(uint2*)((char*)Ps_s[w] + lr * 128 + ((ni * 32 + lg * 8) ^ ((lr & 7) << 4))) =
          make_uint2(p01, p23);
    }

    // ---- O += P V  (pa from wave-local LDS, V from prefetched regs) ----
    #pragma unroll
    for (int ks = 0; ks < 2; ++ks) {
      const int off0 = (ks * 64 + lg * 16) ^ ((lr & 7) << 4);
      bf16x8 pa = *(const bf16x8*)((const char*)Ps_s[w] + lr * 128 + off0);
      __builtin_amdgcn_s_setprio(1);
      #pragma unroll
      for (int ni = 0; ni < 4; ++ni) oacc[ni] = mfma16(pa, vb[ks][ni], oacc[ni]);
      __builtin_amdgcn_s_setprio(0);
    }

    __syncthreads();   // staging drained; all waves done with KsX[cur]
  }

  // row-sum across the 4 lanes sharing lr, then write avt (b, s, c) hi/lo
  float lt = lreg + __shfl_xor(lreg, 16);
  lt += __shfl_xor(lt, 32);
  const float inv = 1.f / lt;
  float invr[4];
  #pragma unroll
  for (int r = 0; r < 4; ++r) invr[r] = __shfl(inv, lg * 4 + r);

  #pragma unroll
  for (int r = 0; r < 4; ++r) {
    const int s = s0 + w * 16 + lg * 4 + r;
    #pragma unroll
    for (int ni = 0; ni < 4; ++ni) {
      const int c = hh * HD + ni * 16 + lr;
      const size_t idx = ((size_t)bz * SEQ + s) * CH + c;
      const float v = oacc[ni][r] * invr[r];
      const u16 hb = f2bf(v);
      av_h[idx] = hb;
      av_l[idx] = f2bf(v - bf2f(hb));
    }
  }
}

extern "C" void kernel_launch(void* const* d_in, const int* in_sizes, int n_in,
                              void* d_out, int out_size, void* d_ws, size_t ws_size,
                              hipStream_t stream) {
  const float* x     = (const float*)d_in[0];  // (8, 512, 32, 32)
  const float* w_qkv = (const float*)d_in[1];  // (1536, 512)
  const float* b_qkv = (const float*)d_in[2];  // (1536,)
  const float* w_o   = (const float*)d_in[3];  // (512, 512)
  const float* b_o   = (const float*)d_in[4];  // (512,)
  float* out = (float*)d_out;                  // (8, 512, 1024) fp32

  char* ws = (char*)d_ws;
  const size_t SZ = (size_t)8 * SEQ * CH * 2;  // one bf16 plane: 8.39 MB
  u16* xt_h = (u16*)(ws + 0 * SZ);             // also avt_h (aliased; xt dead after gemm1)
  u16* xt_l = (u16*)(ws + 1 * SZ);             // also avt_l
  u16* q_h  = (u16*)(ws + 2 * SZ);
  u16* q_l  = (u16*)(ws + 3 * SZ);
  u16* k_h  = (u16*)(ws + 4 * SZ);
  u16* k_l  = (u16*)(ws + 5 * SZ);
  u16* v_h  = (u16*)(ws + 6 * SZ);
  u16* wqkv_h = (u16*)(ws + 7 * SZ);
  u16* wqkv_l = wqkv_h + (size_t)1536 * 512;
  u16* wo_h   = wqkv_l + (size_t)1536 * 512;
  u16* wo_l   = wo_h + (size_t)512 * 512;

  split_plain<<<768, 256, 0, stream>>>(w_qkv, wqkv_h, wqkv_l, (1536 * 512) / 4);
  split_plain<<<256, 256, 0, stream>>>(w_o, wo_h, wo_l, (512 * 512) / 4);
  transpose_split<<<dim3(16, 8, 8), 256, 0, stream>>>(x, xt_h, xt_l);

  gemm_hilo<1><<<dim3(8, 12, 8), 256, 0, stream>>>(
      wqkv_h, wqkv_l, xt_h, xt_l, b_qkv,
      (void*)q_h, (void*)q_l, (void*)k_h, (void*)k_l, (void*)v_h);

  attn_mfma<<<dim3(16, 8, 8), 256, 0, stream>>>(
      q_h, q_l, k_h, k_l, v_h, xt_h, xt_l);   // avt aliases xt

  gemm_hilo<0><<<dim3(8, 4, 8), 256, 0, stream>>>(
      wo_h, wo_l, xt_h, xt_l, b_o,
      (void*)out, nullptr, nullptr, nullptr, nullptr);
}

// Round 6
// 190.570 us; speedup vs baseline: 1.6775x; 1.2661x over previous
//
#include <hip/hip_runtime.h>
#include <cstddef>
#include <cstdint>

#define CH 512
#define SEQ 1024
#define NH 8
#define HD 64

typedef unsigned short u16;
typedef unsigned int u32;
typedef __attribute__((ext_vector_type(8))) short bf16x8;   // 8 bf16 (4 VGPRs)
typedef __attribute__((ext_vector_type(4))) float f32x4;
typedef __attribute__((ext_vector_type(4))) unsigned short u16x4;

// 0.125 * log2(e): folds the 1/sqrt(64) score scale and exp->exp2 conversion
#define SCLQ 0.1803368801111204f

__device__ __forceinline__ u16 f2bf(float f) {
  unsigned u = __float_as_uint(f);
  u += 0x7fffu + ((u >> 16) & 1u);
  return (u16)(u >> 16);
}
__device__ __forceinline__ float bf2f(u16 h) {
  return __uint_as_float(((unsigned)h) << 16);
}
__device__ __forceinline__ u32 cvtpk(float lo, float hi) {
  u32 r;
  asm("v_cvt_pk_bf16_f32 %0, %1, %2" : "=v"(r) : "v"(lo), "v"(hi));
  return r;
}

__device__ __forceinline__ void gld16(void* lds, const void* g) {
  __builtin_amdgcn_global_load_lds(
      (const __attribute__((address_space(1))) unsigned int*)g,
      (__attribute__((address_space(3))) unsigned int*)lds, 16, 0, 0);
}

__device__ __forceinline__ f32x4 mfma16(bf16x8 a, bf16x8 b, f32x4 c) {
  return __builtin_amdgcn_mfma_f32_16x16x32_bf16(a, b, c, 0, 0, 0);
}

// ---------------- split: fp32 -> bf16 hi + lo ----------------
__global__ __launch_bounds__(256) void split_plain(
    const float* __restrict__ in, u16* __restrict__ hi, u16* __restrict__ lo, int n4)
{
  int i = blockIdx.x * 256 + threadIdx.x;
  if (i < n4) {
    float4 v = ((const float4*)in)[i];
    float vv0 = v.x, vv1 = v.y, vv2 = v.z, vv3 = v.w;
    u16x4 h, l;
    h[0] = f2bf(vv0); l[0] = f2bf(vv0 - bf2f(h[0]));
    h[1] = f2bf(vv1); l[1] = f2bf(vv1 - bf2f(h[1]));
    h[2] = f2bf(vv2); l[2] = f2bf(vv2 - bf2f(h[2]));
    h[3] = f2bf(vv3); l[3] = f2bf(vv3 - bf2f(h[3]));
    ((u16x4*)hi)[i] = h;
    ((u16x4*)lo)[i] = l;
  }
}

// x (b, 512 c, 1024 s) fp32 -> xt_hi/lo (b, 1024 s, 512 c) bf16
__global__ __launch_bounds__(256) void transpose_split(
    const float* __restrict__ x, u16* __restrict__ xh, u16* __restrict__ xl)
{
  __shared__ float tile[64][65];
  const int s0 = blockIdx.x * 64, c0 = blockIdx.y * 64, bz = blockIdx.z;
  const int t = threadIdx.x;
  #pragma unroll
  for (int p = 0; p < 16; ++p) {
    int i = p * 256 + t;
    int cl = i >> 6, sl = i & 63;
    tile[cl][sl] = x[((size_t)bz * CH + c0 + cl) * SEQ + s0 + sl];
  }
  __syncthreads();
  #pragma unroll
  for (int p = 0; p < 16; ++p) {
    int i = p * 256 + t;
    int sl = i >> 6, cl = i & 63;
    float v = tile[cl][sl];
    u16 h = f2bf(v);
    size_t idx = ((size_t)bz * SEQ + s0 + sl) * CH + c0 + cl;
    xh[idx] = h;
    xl[idx] = f2bf(v - bf2f(h));
  }
}

// ---------------- hi/lo split-bf16 GEMM ----------------
// C(bz) = A(MxK=512) * BT(bz, N=1024, K=512)^T + bias
// MODE 0: o0 = fp32 out (b, 512, 1024)
// MODE 1: qkv epilogue -> q_hi,q_lo (pre-scaled), k_hi (no lo), v_hi (transposed)
template<int MODE>
__global__ __launch_bounds__(256, 2) void gemm_hilo(
    const u16* __restrict__ Ah, const u16* __restrict__ Al,
    const u16* __restrict__ BTh, const u16* __restrict__ BTl,
    const float* __restrict__ bias,
    void* __restrict__ o0, void* __restrict__ o1, void* __restrict__ o2,
    void* __restrict__ o3, void* __restrict__ o4)
{
  const int bx = blockIdx.x, by = blockIdx.y, bz = blockIdx.z;
  const int m0 = by * 128, n0 = bx * 128;
  const char* Ahc = (const char*)Ah;
  const char* Alc = (const char*)Al;
  const char* Bhc = (const char*)BTh + (size_t)bz * SEQ * CH * 2;
  const char* Blc = (const char*)BTl + (size_t)bz * SEQ * CH * 2;

  // rows of 128B: [32 bf16 hi | 32 bf16 lo], XOR-swizzled by (row&7)<<4
  __shared__ __align__(16) u16 As[128 * 64];
  __shared__ __align__(16) u16 Bs[128 * 64];

  const int t = threadIdx.x, w = t >> 6, lane = t & 63;
  const int lr = lane & 15, lg = lane >> 4;
  const int wr = w >> 1, wc = w & 1;

  f32x4 acc[4][4];
  #pragma unroll
  for (int i = 0; i < 4; ++i)
    #pragma unroll
    for (int j = 0; j < 4; ++j) acc[i][j] = (f32x4){0.f, 0.f, 0.f, 0.f};

  for (int k0 = 0; k0 < CH; k0 += 32) {
    __syncthreads();
    #pragma unroll
    for (int p = 0; p < 4; ++p) {
      const int ldsoff = p * 4096 + w * 1024 + lane * 16;
      const int m = ldsoff >> 7;
      const int W = ldsoff & 127;
      const int Wp = W ^ ((m & 7) << 4);
      const char* src = (Wp < 64 ? Ahc : Alc) + ((size_t)(m0 + m) * CH + k0) * 2 + (Wp & 63);
      gld16((char*)As + p * 4096 + w * 1024, src);
    }
    #pragma unroll
    for (int p = 0; p < 4; ++p) {
      const int ldsoff = p * 4096 + w * 1024 + lane * 16;
      const int n = ldsoff >> 7;
      const int W = ldsoff & 127;
      const int Wp = W ^ ((n & 7) << 4);
      const char* src = (Wp < 64 ? Bhc : Blc) + ((size_t)(n0 + n) * CH + k0) * 2 + (Wp & 63);
      gld16((char*)Bs + p * 4096 + w * 1024, src);
    }
    __syncthreads();

    bf16x8 Afh[4], Afl[4], Bfh[4], Bfl[4];
    #pragma unroll
    for (int mi = 0; mi < 4; ++mi) {
      const int m = wr * 64 + mi * 16 + lr;
      const int swz = (m & 7) << 4;
      Afh[mi] = *(const bf16x8*)((const char*)As + m * 128 + ((lg * 16) ^ swz));
      Afl[mi] = *(const bf16x8*)((const char*)As + m * 128 + ((64 + lg * 16) ^ swz));
    }
    #pragma unroll
    for (int ni = 0; ni < 4; ++ni) {
      const int n = wc * 64 + ni * 16 + lr;
      const int swz = (n & 7) << 4;
      Bfh[ni] = *(const bf16x8*)((const char*)Bs + n * 128 + ((lg * 16) ^ swz));
      Bfl[ni] = *(const bf16x8*)((const char*)Bs + n * 128 + ((64 + lg * 16) ^ swz));
    }
    #pragma unroll
    for (int mi = 0; mi < 4; ++mi) {
      #pragma unroll
      for (int ni = 0; ni < 4; ++ni) {
        acc[mi][ni] = mfma16(Afh[mi], Bfh[ni], acc[mi][ni]);
        acc[mi][ni] = mfma16(Afh[mi], Bfl[ni], acc[mi][ni]);
        acc[mi][ni] = mfma16(Afl[mi], Bfh[ni], acc[mi][ni]);
      }
    }
  }

  if constexpr (MODE == 0) {
    float* Out = (float*)o0 + (size_t)bz * CH * SEQ;
    #pragma unroll
    for (int mi = 0; mi < 4; ++mi) {
      const int mb = m0 + wr * 64 + mi * 16 + lg * 4;
      #pragma unroll
      for (int r = 0; r < 4; ++r) {
        const float bv = bias[mb + r];
        #pragma unroll
        for (int ni = 0; ni < 4; ++ni) {
          const int n = n0 + wc * 64 + ni * 16 + lr;
          Out[(size_t)(mb + r) * SEQ + n] = acc[mi][ni][r] + bv;
        }
      }
    }
  } else {
    u16* qh = (u16*)o0; u16* ql = (u16*)o1;
    u16* kh = (u16*)o2;
    u16* vh = (u16*)o4;
    #pragma unroll
    for (int mi = 0; mi < 4; ++mi) {
      const int mb = m0 + wr * 64 + mi * 16 + lg * 4;   // 4 consecutive m rows
      const int sec = mb >> 9;                          // 0=q 1=k 2=v
      const int h = (mb >> 6) & 7;
      const int d = mb & 63;
      const size_t bh = (size_t)bz * NH + h;
      const float b0 = bias[mb + 0], b1 = bias[mb + 1], b2 = bias[mb + 2], b3 = bias[mb + 3];
      #pragma unroll
      for (int ni = 0; ni < 4; ++ni) {
        const int n = n0 + wc * 64 + ni * 16 + lr;      // s
        float c0 = acc[mi][ni][0] + b0;
        float c1 = acc[mi][ni][1] + b1;
        float c2 = acc[mi][ni][2] + b2;
        float c3 = acc[mi][ni][3] + b3;
        if (sec == 2) {
          u16* dst = vh + (bh * HD + d) * SEQ + n;      // v transposed (b,h,d,s)
          dst[0 * SEQ] = f2bf(c0);
          dst[1 * SEQ] = f2bf(c1);
          dst[2 * SEQ] = f2bf(c2);
          dst[3 * SEQ] = f2bf(c3);
        } else if (sec == 1) {                          // k: hi only
          u16* dsth = kh + (bh * SEQ + n) * HD + d;
          u16x4 hv;
          hv[0] = f2bf(c0); hv[1] = f2bf(c1); hv[2] = f2bf(c2); hv[3] = f2bf(c3);
          *(u16x4*)dsth = hv;
        } else {                                        // q: hi/lo, pre-scaled
          c0 *= SCLQ; c1 *= SCLQ; c2 *= SCLQ; c3 *= SCLQ;
          u16* dsth = qh + (bh * SEQ + n) * HD + d;
          u16* dstl = ql + (bh * SEQ + n) * HD + d;
          u16x4 hv, lv;
          hv[0] = f2bf(c0); lv[0] = f2bf(c0 - bf2f(hv[0]));
          hv[1] = f2bf(c1); lv[1] = f2bf(c1 - bf2f(hv[1]));
          hv[2] = f2bf(c2); lv[2] = f2bf(c2 - bf2f(hv[2]));
          hv[3] = f2bf(c3); lv[3] = f2bf(c3 - bf2f(hv[3]));
          *(u16x4*)dsth = hv;
          *(u16x4*)dstl = lv;
        }
      }
    }
  }
}

// ---------------- flash attention: QBLK=128 (4 waves x 32 q-rows) ----------------
// q: (b,h,1024,64) hi/lo bf16 pre-scaled; k: (b,h,1024,64) hi bf16;
// v: (b,h,64,1024) bf16; out avt: (b,1024,512) hi/lo.
// Swapped QK^T (lane owns softmax row qi=lr); K,V double-buffered LDS via
// coalesced global_load_lds; 1 barrier/tile; P in wave-local LDS with a
// bank-uniform swizzle gsw = ((lr&7)<<4)|(lr&8).
__global__ __launch_bounds__(256, 2) void attn_mfma(
    const u16* __restrict__ q_h, const u16* __restrict__ q_l,
    const u16* __restrict__ k_h, const u16* __restrict__ v_h,
    u16* __restrict__ av_h, u16* __restrict__ av_l)
{
  // XCD swizzle: all 8 q-tiles of one (b,h) land on one XCD (bid%8)
  const int bid = blockIdx.x;
  const int xcd = bid & 7, rr = bid >> 3;
  const int qt = rr & 7, ghi = rr >> 3;
  const int g = ghi * 8 + xcd;
  const int hh = g & 7, bz = g >> 3;
  const int bhead = bz * NH + hh;
  const int s0 = qt * 128;
  const int t = threadIdx.x, w = t >> 6, lane = t & 63;
  const int lr = lane & 15, lg = lane >> 4;
  const int gsw = ((lr & 7) << 4) | (lr & 8);

  __shared__ __align__(16) u16 KsH[2][4096];  // [buf][kj][d] swizzled, 8KB each
  __shared__ __align__(16) u16 Vs[2][4096];   // [buf][d][kj] swizzled, 8KB each
  __shared__ __align__(16) u16 Ps[4][2048];   // per-wave [32 qi][64 kj], gsw-swizzled

  // Q fragments: wave w owns q-rows s0 + w*32 .. +32 (two 16-row halves)
  bf16x8 QBh[2][2], QBl[2][2];
  #pragma unroll
  for (int qh = 0; qh < 2; ++qh) {
    const size_t qrow = (size_t)bhead * SEQ + s0 + w * 32 + qh * 16 + lr;
    #pragma unroll
    for (int ks = 0; ks < 2; ++ks) {
      QBh[qh][ks] = *(const bf16x8*)((const char*)q_h + qrow * 128 + ks * 64 + lg * 16);
      QBl[qh][ks] = *(const bf16x8*)((const char*)q_l + qrow * 128 + ks * 64 + lg * 16);
    }
  }

  const char* Khb = (const char*)k_h + (size_t)bhead * SEQ * 128;
  const char* Vbb = (const char*)v_h + (size_t)bhead * HD * 2048;

  // stage K tile (8KB) + V tile (8KB) into buffer `buf`; linear LDS dest,
  // pre-swizzled global source (rule #21).
  auto STAGE = [&](int buf, int tile) {
    const char* ks = Khb + (size_t)tile * 8192;
    const char* vsrc = Vbb + (size_t)tile * 128;
    #pragma unroll
    for (int p = 0; p < 2; ++p) {
      const int ldsoff = w * 2048 + p * 1024 + lane * 16;
      const int r = ldsoff >> 7;
      const int Wp = (ldsoff & 127) ^ ((r & 7) << 4);
      gld16((char*)KsH[buf] + ldsoff, ks + r * 128 + Wp);
      gld16((char*)Vs[buf] + ldsoff, vsrc + (size_t)r * 2048 + Wp);
    }
  };

  float mreg[2] = {-1e30f, -1e30f}, lreg[2] = {0.f, 0.f};
  f32x4 oacc[2][4];
  #pragma unroll
  for (int qh = 0; qh < 2; ++qh)
    #pragma unroll
    for (int ni = 0; ni < 4; ++ni) oacc[qh][ni] = (f32x4){0.f, 0.f, 0.f, 0.f};

  STAGE(0, 0);
  __syncthreads();

  for (int kt = 0; kt < 16; ++kt) {
    const int cur = kt & 1;
    if (kt < 15) STAGE(cur ^ 1, kt + 1);   // flies under QK+SM+PV, drained by barrier

    // ---- S^T = K Q^T: sc[qh][ni][r] = S[kj=ni*16+lg*4+r][qi=lr] ----
    f32x4 sc[2][4];
    #pragma unroll
    for (int qh = 0; qh < 2; ++qh)
      #pragma unroll
      for (int ni = 0; ni < 4; ++ni) sc[qh][ni] = (f32x4){0.f, 0.f, 0.f, 0.f};
    #pragma unroll
    for (int ks = 0; ks < 2; ++ks) {
      bf16x8 kf[4];
      #pragma unroll
      for (int ni = 0; ni < 4; ++ni) {
        const int row = ni * 16 + lr;
        kf[ni] = *(const bf16x8*)((const char*)KsH[cur] + row * 128 +
                                  ((ks * 64 + lg * 16) ^ ((row & 7) << 4)));
      }
      __builtin_amdgcn_s_setprio(1);
      #pragma unroll
      for (int ni = 0; ni < 4; ++ni) {
        sc[0][ni] = mfma16(kf[ni], QBh[0][ks], sc[0][ni]);
        sc[0][ni] = mfma16(kf[ni], QBl[0][ks], sc[0][ni]);
        sc[1][ni] = mfma16(kf[ni], QBh[1][ks], sc[1][ni]);
        sc[1][ni] = mfma16(kf[ni], QBl[1][ks], sc[1][ni]);
      }
      __builtin_amdgcn_s_setprio(0);
    }

    // ---- per-lane online softmax + P store (bf16, packed) ----
    #pragma unroll
    for (int qh = 0; qh < 2; ++qh) {
      float tm = fmaxf(fmaxf(sc[qh][0][0], sc[qh][0][1]), fmaxf(sc[qh][0][2], sc[qh][0][3]));
      #pragma unroll
      for (int ni = 1; ni < 4; ++ni)
        tm = fmaxf(tm, fmaxf(fmaxf(sc[qh][ni][0], sc[qh][ni][1]),
                             fmaxf(sc[qh][ni][2], sc[qh][ni][3])));
      tm = fmaxf(tm, __shfl_xor(tm, 16));
      tm = fmaxf(tm, __shfl_xor(tm, 32));

      if (!__all(tm <= mreg[qh] + 8.0f)) {       // defer-max: P bounded by 2^8
        const float mn = fmaxf(mreg[qh], tm);
        const float alv = exp2f(mreg[qh] - mn);
        mreg[qh] = mn;
        lreg[qh] *= alv;
        float alr[4];
        #pragma unroll
        for (int r = 0; r < 4; ++r) alr[r] = __shfl(alv, lg * 4 + r);
        #pragma unroll
        for (int ni = 0; ni < 4; ++ni)
          #pragma unroll
          for (int r = 0; r < 4; ++r) oacc[qh][ni][r] *= alr[r];
      }

      char* Pw = (char*)Ps[w] + (qh * 16 + lr) * 128;
      #pragma unroll
      for (int ni = 0; ni < 4; ++ni) {
        const float p0 = exp2f(sc[qh][ni][0] - mreg[qh]);
        const float p1 = exp2f(sc[qh][ni][1] - mreg[qh]);
        const float p2 = exp2f(sc[qh][ni][2] - mreg[qh]);
        const float p3 = exp2f(sc[qh][ni][3] - mreg[qh]);
        lreg[qh] += (p0 + p1) + (p2 + p3);
        *(uint2*)(Pw + ((ni * 32 + lg * 8) ^ gsw)) =
            make_uint2(cvtpk(p0, p1), cvtpk(p2, p3));
      }
    }

    // ---- O += P V  (V fragments reused across both q-halves) ----
    #pragma unroll
    for (int ks = 0; ks < 2; ++ks) {
      bf16x8 vb[4];
      #pragma unroll
      for (int ni = 0; ni < 4; ++ni) {
        const int d = ni * 16 + lr;
        vb[ni] = *(const bf16x8*)((const char*)Vs[cur] + d * 128 +
                                  ((ks * 64 + lg * 16) ^ ((d & 7) << 4)));
      }
      #pragma unroll
      for (int qh = 0; qh < 2; ++qh) {
        const char* Pw = (const char*)Ps[w] + (qh * 16 + lr) * 128;
        const uint2 a = *(const uint2*)(Pw + ((ks * 64 + lg * 16 + 0) ^ gsw));
        const uint2 b = *(const uint2*)(Pw + ((ks * 64 + lg * 16 + 8) ^ gsw));
        union { u32 u[4]; bf16x8 v; } pu;
        pu.u[0] = a.x; pu.u[1] = a.y; pu.u[2] = b.x; pu.u[3] = b.y;
        __builtin_amdgcn_s_setprio(1);
        #pragma unroll
        for (int ni = 0; ni < 4; ++ni)
          oacc[qh][ni] = mfma16(pu.v, vb[ni], oacc[qh][ni]);
        __builtin_amdgcn_s_setprio(0);
      }
    }

    __syncthreads();   // next tile staged; all waves done with buffers[cur]
  }

  // finalize rows, write avt (b, s, c) hi/lo
  #pragma unroll
  for (int qh = 0; qh < 2; ++qh) {
    float lt = lreg[qh] + __shfl_xor(lreg[qh], 16);
    lt += __shfl_xor(lt, 32);
    const float inv = 1.f / lt;
    #pragma unroll
    for (int r = 0; r < 4; ++r) {
      const float invr = __shfl(inv, lg * 4 + r);
      const int s = s0 + w * 32 + qh * 16 + lg * 4 + r;
      #pragma unroll
      for (int ni = 0; ni < 4; ++ni) {
        const int c = hh * HD + ni * 16 + lr;
        const size_t idx = ((size_t)bz * SEQ + s) * CH + c;
        const float v = oacc[qh][ni][r] * invr;
        const u16 hb = f2bf(v);
        av_h[idx] = hb;
        av_l[idx] = f2bf(v - bf2f(hb));
      }
    }
  }
}

extern "C" void kernel_launch(void* const* d_in, const int* in_sizes, int n_in,
                              void* d_out, int out_size, void* d_ws, size_t ws_size,
                              hipStream_t stream) {
  const float* x     = (const float*)d_in[0];  // (8, 512, 32, 32)
  const float* w_qkv = (const float*)d_in[1];  // (1536, 512)
  const float* b_qkv = (const float*)d_in[2];  // (1536,)
  const float* w_o   = (const float*)d_in[3];  // (512, 512)
  const float* b_o   = (const float*)d_in[4];  // (512,)
  float* out = (float*)d_out;                  // (8, 512, 1024) fp32

  char* ws = (char*)d_ws;
  const size_t SZ = (size_t)8 * SEQ * CH * 2;  // one bf16 plane: 8.39 MB
  u16* xt_h = (u16*)(ws + 0 * SZ);             // also avt_h (aliased; xt dead after gemm1)
  u16* xt_l = (u16*)(ws + 1 * SZ);             // also avt_l
  u16* q_h  = (u16*)(ws + 2 * SZ);
  u16* q_l  = (u16*)(ws + 3 * SZ);
  u16* k_h  = (u16*)(ws + 4 * SZ);
  u16* v_h  = (u16*)(ws + 6 * SZ);
  u16* wqkv_h = (u16*)(ws + 7 * SZ);
  u16* wqkv_l = wqkv_h + (size_t)1536 * 512;
  u16* wo_h   = wqkv_l + (size_t)1536 * 512;
  u16* wo_l   = wo_h + (size_t)512 * 512;

  split_plain<<<768, 256, 0, stream>>>(w_qkv, wqkv_h, wqkv_l, (1536 * 512) / 4);
  split_plain<<<256, 256, 0, stream>>>(w_o, wo_h, wo_l, (512 * 512) / 4);
  transpose_split<<<dim3(16, 8, 8), 256, 0, stream>>>(x, xt_h, xt_l);

  gemm_hilo<1><<<dim3(8, 12, 8), 256, 0, stream>>>(
      wqkv_h, wqkv_l, xt_h, xt_l, b_qkv,
      (void*)q_h, (void*)q_l, (void*)k_h, nullptr, (void*)v_h);

  attn_mfma<<<dim3(512), 256, 0, stream>>>(
      q_h, q_l, k_h, v_h, xt_h, xt_l);   // avt aliases xt

  gemm_hilo<0><<<dim3(8, 4, 8), 256, 0, stream>>>(
      wo_h, wo_l, xt_h, xt_l, b_o,
      (void*)out, nullptr, nullptr, nullptr, nullptr);
}

// Round 7
// 185.591 us; speedup vs baseline: 1.7225x; 1.0268x over previous
//
#include <hip/hip_runtime.h>
#include <cstddef>
#include <cstdint>

#define CH 512
#define SEQ 1024
#define NH 8
#define HD 64

typedef unsigned short u16;
typedef unsigned int u32;
typedef __attribute__((ext_vector_type(8))) short bf16x8;   // 8 bf16 (4 VGPRs)
typedef __attribute__((ext_vector_type(4))) float f32x4;
typedef __attribute__((ext_vector_type(4))) unsigned short u16x4;

// 0.125 * log2(e): folds the 1/sqrt(64) score scale and exp->exp2 conversion
#define SCLQ 0.1803368801111204f

__device__ __forceinline__ u16 f2bf(float f) {
  unsigned u = __float_as_uint(f);
  u += 0x7fffu + ((u >> 16) & 1u);
  return (u16)(u >> 16);
}
__device__ __forceinline__ float bf2f(u16 h) {
  return __uint_as_float(((unsigned)h) << 16);
}
__device__ __forceinline__ u32 cvtpk(float lo, float hi) {
  u32 r;
  asm("v_cvt_pk_bf16_f32 %0, %1, %2" : "=v"(r) : "v"(lo), "v"(hi));
  return r;
}

__device__ __forceinline__ void gld16(void* lds, const void* g) {
  __builtin_amdgcn_global_load_lds(
      (const __attribute__((address_space(1))) unsigned int*)g,
      (__attribute__((address_space(3))) unsigned int*)lds, 16, 0, 0);
}

__device__ __forceinline__ f32x4 mfma16(bf16x8 a, bf16x8 b, f32x4 c) {
  return __builtin_amdgcn_mfma_f32_16x16x32_bf16(a, b, c, 0, 0, 0);
}

// ---------------- split: fp32 -> bf16 hi + lo ----------------
__global__ __launch_bounds__(256) void split_plain(
    const float* __restrict__ in, u16* __restrict__ hi, u16* __restrict__ lo, int n4)
{
  int i = blockIdx.x * 256 + threadIdx.x;
  if (i < n4) {
    float4 v = ((const float4*)in)[i];
    float vv0 = v.x, vv1 = v.y, vv2 = v.z, vv3 = v.w;
    u16x4 h, l;
    h[0] = f2bf(vv0); l[0] = f2bf(vv0 - bf2f(h[0]));
    h[1] = f2bf(vv1); l[1] = f2bf(vv1 - bf2f(h[1]));
    h[2] = f2bf(vv2); l[2] = f2bf(vv2 - bf2f(h[2]));
    h[3] = f2bf(vv3); l[3] = f2bf(vv3 - bf2f(h[3]));
    ((u16x4*)hi)[i] = h;
    ((u16x4*)lo)[i] = l;
  }
}

// x (b, 512 c, 1024 s) fp32 -> xt_hi/lo (b, 1024 s, 512 c) bf16
__global__ __launch_bounds__(256) void transpose_split(
    const float* __restrict__ x, u16* __restrict__ xh, u16* __restrict__ xl)
{
  __shared__ float tile[64][65];
  const int s0 = blockIdx.x * 64, c0 = blockIdx.y * 64, bz = blockIdx.z;
  const int t = threadIdx.x;
  #pragma unroll
  for (int p = 0; p < 16; ++p) {
    int i = p * 256 + t;
    int cl = i >> 6, sl = i & 63;
    tile[cl][sl] = x[((size_t)bz * CH + c0 + cl) * SEQ + s0 + sl];
  }
  __syncthreads();
  #pragma unroll
  for (int p = 0; p < 16; ++p) {
    int i = p * 256 + t;
    int sl = i >> 6, cl = i & 63;
    float v = tile[cl][sl];
    u16 h = f2bf(v);
    size_t idx = ((size_t)bz * SEQ + s0 + sl) * CH + c0 + cl;
    xh[idx] = h;
    xl[idx] = f2bf(v - bf2f(h));
  }
}

// ---------------- hi/lo split-bf16 GEMM ----------------
// C(bz) = A(MxK=512) * BT(bz, N=1024, K=512)^T + bias ; tile BM x 128
// MODE 0: o0 = fp32 out (b, 512, 1024)
// MODE 1: qkv epilogue -> q_hi,q_lo (pre-scaled), k_hi (no lo), v_hi (transposed)
template<int MODE, int BM>
__global__ __launch_bounds__(256, 2) void gemm_hilo(
    const u16* __restrict__ Ah, const u16* __restrict__ Al,
    const u16* __restrict__ BTh, const u16* __restrict__ BTl,
    const float* __restrict__ bias,
    void* __restrict__ o0, void* __restrict__ o1, void* __restrict__ o2,
    void* __restrict__ o3, void* __restrict__ o4)
{
  constexpr int WM = BM / 2;     // wave M extent
  constexpr int MI = WM / 16;    // m fragments per wave
  const int bx = blockIdx.x, by = blockIdx.y, bz = blockIdx.z;
  const int m0 = by * BM, n0 = bx * 128;
  const char* Ahc = (const char*)Ah;
  const char* Alc = (const char*)Al;
  const char* Bhc = (const char*)BTh + (size_t)bz * SEQ * CH * 2;
  const char* Blc = (const char*)BTl + (size_t)bz * SEQ * CH * 2;

  // rows of 128B: [32 bf16 hi | 32 bf16 lo], XOR-swizzled by (row&7)<<4
  __shared__ __align__(16) u16 As[BM * 64];
  __shared__ __align__(16) u16 Bs[128 * 64];

  const int t = threadIdx.x, w = t >> 6, lane = t & 63;
  const int lr = lane & 15, lg = lane >> 4;
  const int wr = w >> 1, wc = w & 1;

  f32x4 acc[MI][4];
  #pragma unroll
  for (int i = 0; i < MI; ++i)
    #pragma unroll
    for (int j = 0; j < 4; ++j) acc[i][j] = (f32x4){0.f, 0.f, 0.f, 0.f};

  for (int k0 = 0; k0 < CH; k0 += 32) {
    __syncthreads();
    #pragma unroll
    for (int p = 0; p < BM / 32; ++p) {
      const int ldsoff = p * 4096 + w * 1024 + lane * 16;
      const int m = ldsoff >> 7;
      const int W = ldsoff & 127;
      const int Wp = W ^ ((m & 7) << 4);
      const char* src = (Wp < 64 ? Ahc : Alc) + ((size_t)(m0 + m) * CH + k0) * 2 + (Wp & 63);
      gld16((char*)As + p * 4096 + w * 1024, src);
    }
    #pragma unroll
    for (int p = 0; p < 4; ++p) {
      const int ldsoff = p * 4096 + w * 1024 + lane * 16;
      const int n = ldsoff >> 7;
      const int W = ldsoff & 127;
      const int Wp = W ^ ((n & 7) << 4);
      const char* src = (Wp < 64 ? Bhc : Blc) + ((size_t)(n0 + n) * CH + k0) * 2 + (Wp & 63);
      gld16((char*)Bs + p * 4096 + w * 1024, src);
    }
    __syncthreads();

    bf16x8 Afh[MI], Afl[MI], Bfh[4], Bfl[4];
    #pragma unroll
    for (int mi = 0; mi < MI; ++mi) {
      const int m = wr * WM + mi * 16 + lr;
      const int swz = (m & 7) << 4;
      Afh[mi] = *(const bf16x8*)((const char*)As + m * 128 + ((lg * 16) ^ swz));
      Afl[mi] = *(const bf16x8*)((const char*)As + m * 128 + ((64 + lg * 16) ^ swz));
    }
    #pragma unroll
    for (int ni = 0; ni < 4; ++ni) {
      const int n = wc * 64 + ni * 16 + lr;
      const int swz = (n & 7) << 4;
      Bfh[ni] = *(const bf16x8*)((const char*)Bs + n * 128 + ((lg * 16) ^ swz));
      Bfl[ni] = *(const bf16x8*)((const char*)Bs + n * 128 + ((64 + lg * 16) ^ swz));
    }
    #pragma unroll
    for (int mi = 0; mi < MI; ++mi) {
      #pragma unroll
      for (int ni = 0; ni < 4; ++ni) {
        acc[mi][ni] = mfma16(Afh[mi], Bfh[ni], acc[mi][ni]);
        acc[mi][ni] = mfma16(Afh[mi], Bfl[ni], acc[mi][ni]);
        acc[mi][ni] = mfma16(Afl[mi], Bfh[ni], acc[mi][ni]);
      }
    }
  }

  if constexpr (MODE == 0) {
    float* Out = (float*)o0 + (size_t)bz * CH * SEQ;
    #pragma unroll
    for (int mi = 0; mi < MI; ++mi) {
      const int mb = m0 + wr * WM + mi * 16 + lg * 4;
      #pragma unroll
      for (int r = 0; r < 4; ++r) {
        const float bv = bias[mb + r];
        #pragma unroll
        for (int ni = 0; ni < 4; ++ni) {
          const int n = n0 + wc * 64 + ni * 16 + lr;
          Out[(size_t)(mb + r) * SEQ + n] = acc[mi][ni][r] + bv;
        }
      }
    }
  } else {
    u16* qh = (u16*)o0; u16* ql = (u16*)o1;
    u16* kh = (u16*)o2;
    u16* vh = (u16*)o4;
    #pragma unroll
    for (int mi = 0; mi < MI; ++mi) {
      const int mb = m0 + wr * WM + mi * 16 + lg * 4;   // 4 consecutive m rows
      const int sec = mb >> 9;                          // 0=q 1=k 2=v
      const int h = (mb >> 6) & 7;
      const int d = mb & 63;
      const size_t bh = (size_t)bz * NH + h;
      const float b0 = bias[mb + 0], b1 = bias[mb + 1], b2 = bias[mb + 2], b3 = bias[mb + 3];
      #pragma unroll
      for (int ni = 0; ni < 4; ++ni) {
        const int n = n0 + wc * 64 + ni * 16 + lr;      // s
        float c0 = acc[mi][ni][0] + b0;
        float c1 = acc[mi][ni][1] + b1;
        float c2 = acc[mi][ni][2] + b2;
        float c3 = acc[mi][ni][3] + b3;
        if (sec == 2) {
          u16* dst = vh + (bh * HD + d) * SEQ + n;      // v transposed (b,h,d,s)
          dst[0 * SEQ] = f2bf(c0);
          dst[1 * SEQ] = f2bf(c1);
          dst[2 * SEQ] = f2bf(c2);
          dst[3 * SEQ] = f2bf(c3);
        } else if (sec == 1) {                          // k: hi only
          u16* dsth = kh + (bh * SEQ + n) * HD + d;
          u16x4 hv;
          hv[0] = f2bf(c0); hv[1] = f2bf(c1); hv[2] = f2bf(c2); hv[3] = f2bf(c3);
          *(u16x4*)dsth = hv;
        } else {                                        // q: hi/lo, pre-scaled
          c0 *= SCLQ; c1 *= SCLQ; c2 *= SCLQ; c3 *= SCLQ;
          u16* dsth = qh + (bh * SEQ + n) * HD + d;
          u16* dstl = ql + (bh * SEQ + n) * HD + d;
          u16x4 hv, lv;
          hv[0] = f2bf(c0); lv[0] = f2bf(c0 - bf2f(hv[0]));
          hv[1] = f2bf(c1); lv[1] = f2bf(c1 - bf2f(hv[1]));
          hv[2] = f2bf(c2); lv[2] = f2bf(c2 - bf2f(hv[2]));
          hv[3] = f2bf(c3); lv[3] = f2bf(c3 - bf2f(hv[3]));
          *(u16x4*)dsth = hv;
          *(u16x4*)dstl = lv;
        }
      }
    }
  }
}

// ---------------- flash attention: QBLK=64 (4 waves x 16 q-rows) ----------------
// q: (b,h,1024,64) hi/lo bf16 pre-scaled; k: (b,h,1024,64) hi bf16;
// v: (b,h,64,1024) bf16; out avt: (b,1024,512) hi/lo.
// Swapped QK^T (lane owns softmax row qi=lr); K,V double-buffered LDS via
// coalesced global_load_lds; 1 barrier/tile; LDS 40KB -> 4 blocks/CU,
// 16 waves/CU for cross-wave MFMA/VALU overlap (m114).
__global__ __launch_bounds__(256, 4) void attn_mfma(
    const u16* __restrict__ q_h, const u16* __restrict__ q_l,
    const u16* __restrict__ k_h, const u16* __restrict__ v_h,
    u16* __restrict__ av_h, u16* __restrict__ av_l)
{
  // XCD swizzle: all 16 q-tiles of one (b,h) land on one XCD (bid%8)
  const int bid = blockIdx.x;
  const int xcd = bid & 7, rr = bid >> 3;      // rr 0..127
  const int qt = rr & 15, ghi = rr >> 4;       // ghi 0..7
  const int g = ghi * 8 + xcd;                 // (b,h) group 0..63
  const int hh = g & 7, bz = g >> 3;
  const int bhead = bz * NH + hh;
  const int s0 = qt * 64;
  const int t = threadIdx.x, w = t >> 6, lane = t & 63;
  const int lr = lane & 15, lg = lane >> 4;
  const int gsw = ((lr & 7) << 4) | (lr & 8);

  __shared__ __align__(16) u16 KsH[2][4096];  // [buf][kj][d] swizzled, 8KB each
  __shared__ __align__(16) u16 Vs[2][4096];   // [buf][d][kj] swizzled, 8KB each
  __shared__ __align__(16) u16 Ps[4][1024];   // per-wave [16 qi][64 kj], gsw-swizzled

  // Q fragments: wave w owns q-rows s0 + w*16 .. +16
  bf16x8 QBh[2], QBl[2];
  {
    const size_t qrow = (size_t)bhead * SEQ + s0 + w * 16 + lr;
    #pragma unroll
    for (int ks = 0; ks < 2; ++ks) {
      QBh[ks] = *(const bf16x8*)((const char*)q_h + qrow * 128 + ks * 64 + lg * 16);
      QBl[ks] = *(const bf16x8*)((const char*)q_l + qrow * 128 + ks * 64 + lg * 16);
    }
  }

  const char* Khb = (const char*)k_h + (size_t)bhead * SEQ * 128;
  const char* Vbb = (const char*)v_h + (size_t)bhead * HD * 2048;

  // stage K tile (8KB) + V tile (8KB); linear LDS dest, pre-swizzled source.
  auto STAGE = [&](int buf, int tile) {
    const char* ks = Khb + (size_t)tile * 8192;
    const char* vsrc = Vbb + (size_t)tile * 128;
    #pragma unroll
    for (int p = 0; p < 2; ++p) {
      const int ldsoff = w * 2048 + p * 1024 + lane * 16;
      const int r = ldsoff >> 7;
      const int Wp = (ldsoff & 127) ^ ((r & 7) << 4);
      gld16((char*)KsH[buf] + ldsoff, ks + r * 128 + Wp);
      gld16((char*)Vs[buf] + ldsoff, vsrc + (size_t)r * 2048 + Wp);
    }
  };

  float mreg = -1e30f, lreg = 0.f;
  f32x4 oacc[4];
  #pragma unroll
  for (int ni = 0; ni < 4; ++ni) oacc[ni] = (f32x4){0.f, 0.f, 0.f, 0.f};

  STAGE(0, 0);
  __syncthreads();

  for (int kt = 0; kt < 16; ++kt) {
    const int cur = kt & 1;
    if (kt < 15) STAGE(cur ^ 1, kt + 1);   // flies under QK+SM+PV, drained by barrier

    // ---- S^T = K Q^T: sc[ni][r] = S[kj=ni*16+lg*4+r][qi=lr] ----
    f32x4 sc[4];
    #pragma unroll
    for (int ni = 0; ni < 4; ++ni) sc[ni] = (f32x4){0.f, 0.f, 0.f, 0.f};
    #pragma unroll
    for (int ks = 0; ks < 2; ++ks) {
      bf16x8 kf[4];
      #pragma unroll
      for (int ni = 0; ni < 4; ++ni) {
        const int row = ni * 16 + lr;
        kf[ni] = *(const bf16x8*)((const char*)KsH[cur] + row * 128 +
                                  ((ks * 64 + lg * 16) ^ ((row & 7) << 4)));
      }
      __builtin_amdgcn_s_setprio(1);
      #pragma unroll
      for (int ni = 0; ni < 4; ++ni) {
        sc[ni] = mfma16(kf[ni], QBh[ks], sc[ni]);
        sc[ni] = mfma16(kf[ni], QBl[ks], sc[ni]);
      }
      __builtin_amdgcn_s_setprio(0);
    }

    // ---- per-lane online softmax + P store (bf16, packed) ----
    float tm = fmaxf(fmaxf(sc[0][0], sc[0][1]), fmaxf(sc[0][2], sc[0][3]));
    #pragma unroll
    for (int ni = 1; ni < 4; ++ni)
      tm = fmaxf(tm, fmaxf(fmaxf(sc[ni][0], sc[ni][1]), fmaxf(sc[ni][2], sc[ni][3])));
    tm = fmaxf(tm, __shfl_xor(tm, 16));
    tm = fmaxf(tm, __shfl_xor(tm, 32));

    if (!__all(tm <= mreg + 8.0f)) {       // defer-max: P bounded by 2^8
      const float mn = fmaxf(mreg, tm);
      const float alv = exp2f(mreg - mn);
      mreg = mn;
      lreg *= alv;
      float alr[4];
      #pragma unroll
      for (int r = 0; r < 4; ++r) alr[r] = __shfl(alv, lg * 4 + r);
      #pragma unroll
      for (int ni = 0; ni < 4; ++ni)
        #pragma unroll
        for (int r = 0; r < 4; ++r) oacc[ni][r] *= alr[r];
    }

    char* Pw = (char*)Ps[w] + lr * 128;
    #pragma unroll
    for (int ni = 0; ni < 4; ++ni) {
      const float p0 = exp2f(sc[ni][0] - mreg);
      const float p1 = exp2f(sc[ni][1] - mreg);
      const float p2 = exp2f(sc[ni][2] - mreg);
      const float p3 = exp2f(sc[ni][3] - mreg);
      lreg += (p0 + p1) + (p2 + p3);
      *(uint2*)(Pw + ((ni * 32 + lg * 8) ^ gsw)) =
          make_uint2(cvtpk(p0, p1), cvtpk(p2, p3));
    }

    // ---- O += P V ----
    #pragma unroll
    for (int ks = 0; ks < 2; ++ks) {
      bf16x8 vb[4];
      #pragma unroll
      for (int ni = 0; ni < 4; ++ni) {
        const int d = ni * 16 + lr;
        vb[ni] = *(const bf16x8*)((const char*)Vs[cur] + d * 128 +
                                  ((ks * 64 + lg * 16) ^ ((d & 7) << 4)));
      }
      const uint2 a = *(const uint2*)(Pw + ((ks * 64 + lg * 16 + 0) ^ gsw));
      const uint2 b = *(const uint2*)(Pw + ((ks * 64 + lg * 16 + 8) ^ gsw));
      union { u32 u[4]; bf16x8 v; } pu;
      pu.u[0] = a.x; pu.u[1] = a.y; pu.u[2] = b.x; pu.u[3] = b.y;
      __builtin_amdgcn_s_setprio(1);
      #pragma unroll
      for (int ni = 0; ni < 4; ++ni)
        oacc[ni] = mfma16(pu.v, vb[ni], oacc[ni]);
      __builtin_amdgcn_s_setprio(0);
    }

    __syncthreads();   // next tile staged; all waves done with buffers[cur]
  }

  // finalize rows, write avt (b, s, c) hi/lo
  float lt = lreg + __shfl_xor(lreg, 16);
  lt += __shfl_xor(lt, 32);
  const float inv = 1.f / lt;
  #pragma unroll
  for (int r = 0; r < 4; ++r) {
    const float invr = __shfl(inv, lg * 4 + r);
    const int s = s0 + w * 16 + lg * 4 + r;
    #pragma unroll
    for (int ni = 0; ni < 4; ++ni) {
      const int c = hh * HD + ni * 16 + lr;
      const size_t idx = ((size_t)bz * SEQ + s) * CH + c;
      const float v = oacc[ni][r] * invr;
      const u16 hb = f2bf(v);
      av_h[idx] = hb;
      av_l[idx] = f2bf(v - bf2f(hb));
    }
  }
}

extern "C" void kernel_launch(void* const* d_in, const int* in_sizes, int n_in,
                              void* d_out, int out_size, void* d_ws, size_t ws_size,
                              hipStream_t stream) {
  const float* x     = (const float*)d_in[0];  // (8, 512, 32, 32)
  const float* w_qkv = (const float*)d_in[1];  // (1536, 512)
  const float* b_qkv = (const float*)d_in[2];  // (1536,)
  const float* w_o   = (const float*)d_in[3];  // (512, 512)
  const float* b_o   = (const float*)d_in[4];  // (512,)
  float* out = (float*)d_out;                  // (8, 512, 1024) fp32

  char* ws = (char*)d_ws;
  const size_t SZ = (size_t)8 * SEQ * CH * 2;  // one bf16 plane: 8.39 MB
  u16* xt_h = (u16*)(ws + 0 * SZ);             // also avt_h (aliased; xt dead after gemm1)
  u16* xt_l = (u16*)(ws + 1 * SZ);             // also avt_l
  u16* q_h  = (u16*)(ws + 2 * SZ);
  u16* q_l  = (u16*)(ws + 3 * SZ);
  u16* k_h  = (u16*)(ws + 4 * SZ);
  u16* v_h  = (u16*)(ws + 6 * SZ);
  u16* wqkv_h = (u16*)(ws + 7 * SZ);
  u16* wqkv_l = wqkv_h + (size_t)1536 * 512;
  u16* wo_h   = wqkv_l + (size_t)1536 * 512;
  u16* wo_l   = wo_h + (size_t)512 * 512;

  split_plain<<<768, 256, 0, stream>>>(w_qkv, wqkv_h, wqkv_l, (1536 * 512) / 4);
  split_plain<<<256, 256, 0, stream>>>(w_o, wo_h, wo_l, (512 * 512) / 4);
  transpose_split<<<dim3(16, 8, 8), 256, 0, stream>>>(x, xt_h, xt_l);

  gemm_hilo<1, 128><<<dim3(8, 12, 8), 256, 0, stream>>>(
      wqkv_h, wqkv_l, xt_h, xt_l, b_qkv,
      (void*)q_h, (void*)q_l, (void*)k_h, nullptr, (void*)v_h);

  attn_mfma<<<dim3(1024), 256, 0, stream>>>(
      q_h, q_l, k_h, v_h, xt_h, xt_l);   // avt aliases xt

  gemm_hilo<0, 64><<<dim3(8, 8, 8), 256, 0, stream>>>(
      wo_h, wo_l, xt_h, xt_l, b_o,
      (void*)out, nullptr, nullptr, nullptr, nullptr);
}

// Round 8
// 182.802 us; speedup vs baseline: 1.7487x; 1.0153x over previous
//
#include <hip/hip_runtime.h>
#include <cstddef>
#include <cstdint>

#define CH 512
#define SEQ 1024
#define NH 8
#define HD 64

typedef unsigned short u16;
typedef unsigned int u32;
typedef __attribute__((ext_vector_type(8))) short bf16x8;   // 8 bf16 (4 VGPRs)
typedef __attribute__((ext_vector_type(4))) float f32x4;
typedef __attribute__((ext_vector_type(4))) unsigned short u16x4;

// 0.125 * log2(e): folds the 1/sqrt(64) score scale and exp->exp2 conversion
#define SCLQ 0.1803368801111204f

__device__ __forceinline__ u16 f2bf(float f) {
  unsigned u = __float_as_uint(f);
  u += 0x7fffu + ((u >> 16) & 1u);
  return (u16)(u >> 16);
}
__device__ __forceinline__ float bf2f(u16 h) {
  return __uint_as_float(((unsigned)h) << 16);
}
__device__ __forceinline__ u32 cvtpk(float lo, float hi) {
  u32 r;
  asm("v_cvt_pk_bf16_f32 %0, %1, %2" : "=v"(r) : "v"(lo), "v"(hi));
  return r;
}

__device__ __forceinline__ void gld16(void* lds, const void* g) {
  __builtin_amdgcn_global_load_lds(
      (const __attribute__((address_space(1))) unsigned int*)g,
      (__attribute__((address_space(3))) unsigned int*)lds, 16, 0, 0);
}

__device__ __forceinline__ f32x4 mfma16(bf16x8 a, bf16x8 b, f32x4 c) {
  return __builtin_amdgcn_mfma_f32_16x16x32_bf16(a, b, c, 0, 0, 0);
}

// ---------------- split both weight matrices: fp32 -> bf16 hi + lo ----------------
// blocks 0..767: w_qkv (1536*512); blocks 768..1023: w_o (512*512)
__global__ __launch_bounds__(256) void split_both(
    const float* __restrict__ wqkv, u16* __restrict__ wqkv_h, u16* __restrict__ wqkv_l,
    const float* __restrict__ wo, u16* __restrict__ wo_h, u16* __restrict__ wo_l)
{
  const int b = blockIdx.x;
  const float* in; u16* hi; u16* lo; int i;
  if (b < 768) { in = wqkv; hi = wqkv_h; lo = wqkv_l; i = b * 256 + threadIdx.x; }
  else         { in = wo;   hi = wo_h;   lo = wo_l;   i = (b - 768) * 256 + threadIdx.x; }
  float4 v = ((const float4*)in)[i];
  u16x4 h, l;
  h[0] = f2bf(v.x); l[0] = f2bf(v.x - bf2f(h[0]));
  h[1] = f2bf(v.y); l[1] = f2bf(v.y - bf2f(h[1]));
  h[2] = f2bf(v.z); l[2] = f2bf(v.z - bf2f(h[2]));
  h[3] = f2bf(v.w); l[3] = f2bf(v.w - bf2f(h[3]));
  ((u16x4*)hi)[i] = h;
  ((u16x4*)lo)[i] = l;
}

// x (b, 512 c, 1024 s) fp32 -> xt_hi/lo (b, 1024 s, 512 c) bf16
__global__ __launch_bounds__(256) void transpose_split(
    const float* __restrict__ x, u16* __restrict__ xh, u16* __restrict__ xl)
{
  __shared__ float tile[64][65];
  const int s0 = blockIdx.x * 64, c0 = blockIdx.y * 64, bz = blockIdx.z;
  const int t = threadIdx.x;
  #pragma unroll
  for (int p = 0; p < 16; ++p) {
    int i = p * 256 + t;
    int cl = i >> 6, sl = i & 63;
    tile[cl][sl] = x[((size_t)bz * CH + c0 + cl) * SEQ + s0 + sl];
  }
  __syncthreads();
  #pragma unroll
  for (int p = 0; p < 16; ++p) {
    int i = p * 256 + t;
    int sl = i >> 6, cl = i & 63;
    float v = tile[cl][sl];
    u16 h = f2bf(v);
    size_t idx = ((size_t)bz * SEQ + s0 + sl) * CH + c0 + cl;
    xh[idx] = h;
    xl[idx] = f2bf(v - bf2f(h));
  }
}

// ---------------- hi/lo split-bf16 GEMM ----------------
// C(bz) = A(MxK=512) * BT(bz, N=1024, K=512)^T + bias ; tile BM x 128
// MODE 0: o0 = fp32 out (b, 512, 1024)
// MODE 1: qkv epilogue -> q_hi,q_lo (pre-scaled), k_hi (no lo), v_hi (transposed)
template<int MODE, int BM>
__global__ __launch_bounds__(256, 2) void gemm_hilo(
    const u16* __restrict__ Ah, const u16* __restrict__ Al,
    const u16* __restrict__ BTh, const u16* __restrict__ BTl,
    const float* __restrict__ bias,
    void* __restrict__ o0, void* __restrict__ o1, void* __restrict__ o2,
    void* __restrict__ o3, void* __restrict__ o4)
{
  constexpr int WM = BM / 2;     // wave M extent
  constexpr int MI = WM / 16;    // m fragments per wave
  const int bx = blockIdx.x, by = blockIdx.y, bz = blockIdx.z;
  const int m0 = by * BM, n0 = bx * 128;
  const char* Ahc = (const char*)Ah;
  const char* Alc = (const char*)Al;
  const char* Bhc = (const char*)BTh + (size_t)bz * SEQ * CH * 2;
  const char* Blc = (const char*)BTl + (size_t)bz * SEQ * CH * 2;

  // rows of 128B: [32 bf16 hi | 32 bf16 lo], XOR-swizzled by (row&7)<<4
  __shared__ __align__(16) u16 As[BM * 64];
  __shared__ __align__(16) u16 Bs[128 * 64];

  const int t = threadIdx.x, w = t >> 6, lane = t & 63;
  const int lr = lane & 15, lg = lane >> 4;
  const int wr = w >> 1, wc = w & 1;

  f32x4 acc[MI][4];
  #pragma unroll
  for (int i = 0; i < MI; ++i)
    #pragma unroll
    for (int j = 0; j < 4; ++j) acc[i][j] = (f32x4){0.f, 0.f, 0.f, 0.f};

  for (int k0 = 0; k0 < CH; k0 += 32) {
    __syncthreads();
    #pragma unroll
    for (int p = 0; p < BM / 32; ++p) {
      const int ldsoff = p * 4096 + w * 1024 + lane * 16;
      const int m = ldsoff >> 7;
      const int W = ldsoff & 127;
      const int Wp = W ^ ((m & 7) << 4);
      const char* src = (Wp < 64 ? Ahc : Alc) + ((size_t)(m0 + m) * CH + k0) * 2 + (Wp & 63);
      gld16((char*)As + p * 4096 + w * 1024, src);
    }
    #pragma unroll
    for (int p = 0; p < 4; ++p) {
      const int ldsoff = p * 4096 + w * 1024 + lane * 16;
      const int n = ldsoff >> 7;
      const int W = ldsoff & 127;
      const int Wp = W ^ ((n & 7) << 4);
      const char* src = (Wp < 64 ? Bhc : Blc) + ((size_t)(n0 + n) * CH + k0) * 2 + (Wp & 63);
      gld16((char*)Bs + p * 4096 + w * 1024, src);
    }
    __syncthreads();

    bf16x8 Afh[MI], Afl[MI], Bfh[4], Bfl[4];
    #pragma unroll
    for (int mi = 0; mi < MI; ++mi) {
      const int m = wr * WM + mi * 16 + lr;
      const int swz = (m & 7) << 4;
      Afh[mi] = *(const bf16x8*)((const char*)As + m * 128 + ((lg * 16) ^ swz));
      Afl[mi] = *(const bf16x8*)((const char*)As + m * 128 + ((64 + lg * 16) ^ swz));
    }
    #pragma unroll
    for (int ni = 0; ni < 4; ++ni) {
      const int n = wc * 64 + ni * 16 + lr;
      const int swz = (n & 7) << 4;
      Bfh[ni] = *(const bf16x8*)((const char*)Bs + n * 128 + ((lg * 16) ^ swz));
      Bfl[ni] = *(const bf16x8*)((const char*)Bs + n * 128 + ((64 + lg * 16) ^ swz));
    }
    #pragma unroll
    for (int mi = 0; mi < MI; ++mi) {
      #pragma unroll
      for (int ni = 0; ni < 4; ++ni) {
        acc[mi][ni] = mfma16(Afh[mi], Bfh[ni], acc[mi][ni]);
        acc[mi][ni] = mfma16(Afh[mi], Bfl[ni], acc[mi][ni]);
        acc[mi][ni] = mfma16(Afl[mi], Bfh[ni], acc[mi][ni]);
      }
    }
  }

  if constexpr (MODE == 0) {
    float* Out = (float*)o0 + (size_t)bz * CH * SEQ;
    #pragma unroll
    for (int mi = 0; mi < MI; ++mi) {
      const int mb = m0 + wr * WM + mi * 16 + lg * 4;
      #pragma unroll
      for (int r = 0; r < 4; ++r) {
        const float bv = bias[mb + r];
        #pragma unroll
        for (int ni = 0; ni < 4; ++ni) {
          const int n = n0 + wc * 64 + ni * 16 + lr;
          Out[(size_t)(mb + r) * SEQ + n] = acc[mi][ni][r] + bv;
        }
      }
    }
  } else {
    u16* qh = (u16*)o0; u16* ql = (u16*)o1;
    u16* kh = (u16*)o2;
    u16* vh = (u16*)o4;
    #pragma unroll
    for (int mi = 0; mi < MI; ++mi) {
      const int mb = m0 + wr * WM + mi * 16 + lg * 4;   // 4 consecutive m rows
      const int sec = mb >> 9;                          // 0=q 1=k 2=v
      const int h = (mb >> 6) & 7;
      const int d = mb & 63;
      const size_t bh = (size_t)bz * NH + h;
      const float b0 = bias[mb + 0], b1 = bias[mb + 1], b2 = bias[mb + 2], b3 = bias[mb + 3];
      #pragma unroll
      for (int ni = 0; ni < 4; ++ni) {
        const int n = n0 + wc * 64 + ni * 16 + lr;      // s
        float c0 = acc[mi][ni][0] + b0;
        float c1 = acc[mi][ni][1] + b1;
        float c2 = acc[mi][ni][2] + b2;
        float c3 = acc[mi][ni][3] + b3;
        if (sec == 2) {
          u16* dst = vh + (bh * HD + d) * SEQ + n;      // v transposed (b,h,d,s)
          dst[0 * SEQ] = f2bf(c0);
          dst[1 * SEQ] = f2bf(c1);
          dst[2 * SEQ] = f2bf(c2);
          dst[3 * SEQ] = f2bf(c3);
        } else if (sec == 1) {                          // k: hi only
          u16* dsth = kh + (bh * SEQ + n) * HD + d;
          u16x4 hv;
          hv[0] = f2bf(c0); hv[1] = f2bf(c1); hv[2] = f2bf(c2); hv[3] = f2bf(c3);
          *(u16x4*)dsth = hv;
        } else {                                        // q: hi/lo, pre-scaled
          c0 *= SCLQ; c1 *= SCLQ; c2 *= SCLQ; c3 *= SCLQ;
          u16* dsth = qh + (bh * SEQ + n) * HD + d;
          u16* dstl = ql + (bh * SEQ + n) * HD + d;
          u16x4 hv, lv;
          hv[0] = f2bf(c0); lv[0] = f2bf(c0 - bf2f(hv[0]));
          hv[1] = f2bf(c1); lv[1] = f2bf(c1 - bf2f(hv[1]));
          hv[2] = f2bf(c2); lv[2] = f2bf(c2 - bf2f(hv[2]));
          hv[3] = f2bf(c3); lv[3] = f2bf(c3 - bf2f(hv[3]));
          *(u16x4*)dsth = hv;
          *(u16x4*)dstl = lv;
        }
      }
    }
  }
}

// ---------------- flash attention: QBLK=64, fully-unrolled, MFMA row-sum ----------------
// q: (b,h,1024,64) hi/lo bf16 pre-scaled; k: (b,h,1024,64) hi bf16;
// v: (b,h,64,1024) bf16; out avt: (b,1024,512) hi/lo.
// Swapped QK^T (lane owns softmax row qi=lr). kt loop fully unrolled so all
// LDS addresses are hoisted pointers + offset immediates. Row-sum l computed
// on the MFMA pipe via ls = mfma(P, ones, ls) (D rows align with oacc rows),
// replacing 16 VALU adds/tile and the epilogue shuffle reduction.
__global__ __launch_bounds__(256, 4) void attn_mfma(
    const u16* __restrict__ q_h, const u16* __restrict__ q_l,
    const u16* __restrict__ k_h, const u16* __restrict__ v_h,
    u16* __restrict__ av_h, u16* __restrict__ av_l)
{
  // XCD swizzle: all 16 q-tiles of one (b,h) land on one XCD (bid%8)
  const int bid = blockIdx.x;
  const int xcd = bid & 7, rr = bid >> 3;      // rr 0..127
  const int qt = rr & 15, ghi = rr >> 4;       // ghi 0..7
  const int g = ghi * 8 + xcd;                 // (b,h) group 0..63
  const int hh = g & 7, bz = g >> 3;
  const int bhead = bz * NH + hh;
  const int s0 = qt * 64;
  const int t = threadIdx.x, w = t >> 6, lane = t & 63;
  const int lr = lane & 15, lg = lane >> 4;
  const int gsw = ((lr & 7) << 4) | (lr & 8);

  // single LDS block (40KB): K buf0 @0, K buf1 @8192, V buf0 @16384,
  // V buf1 @24576, P @32768 + w*2048 (per-wave 16 qi x 64 kj bf16)
  __shared__ __align__(16) char SH[40960];

  // Q fragments: wave w owns q-rows s0 + w*16 .. +16
  bf16x8 QBh[2], QBl[2];
  {
    const size_t qrow = (size_t)bhead * SEQ + s0 + w * 16 + lr;
    #pragma unroll
    for (int ks = 0; ks < 2; ++ks) {
      QBh[ks] = *(const bf16x8*)((const char*)q_h + qrow * 128 + ks * 64 + lg * 16);
      QBl[ks] = *(const bf16x8*)((const char*)q_l + qrow * 128 + ks * 64 + lg * 16);
    }
  }

  const char* Khb = (const char*)k_h + (size_t)bhead * SEQ * 128;
  const char* Vbb = (const char*)v_h + (size_t)bhead * HD * 2048;

  // hoisted LDS read pointers (K and V share the offset formula; V at +16384)
  const char* kp[2][4];
  #pragma unroll
  for (int ks = 0; ks < 2; ++ks)
    #pragma unroll
    for (int ni = 0; ni < 4; ++ni) {
      const int row = ni * 16 + lr;
      kp[ks][ni] = SH + row * 128 + ((ks * 64 + lg * 16) ^ ((row & 7) << 4));
    }
  char* pwp = SH + 32768 + w * 2048 + lr * 128;
  char* pw[4];
  #pragma unroll
  for (int ni = 0; ni < 4; ++ni) pw[ni] = pwp + ((ni * 32 + lg * 8) ^ gsw);
  const char* pr[2][2];
  #pragma unroll
  for (int ks = 0; ks < 2; ++ks)
    #pragma unroll
    for (int h2 = 0; h2 < 2; ++h2)
      pr[ks][h2] = pwp + ((ks * 64 + lg * 16 + h2 * 8) ^ gsw);

  // stage K tile (8KB) + V tile (8KB); linear LDS dest, pre-swizzled source.
  auto STAGE = [&](int buf, int tile) {
    const char* ksrc = Khb + (size_t)tile * 8192;
    const char* vsrc = Vbb + (size_t)tile * 128;
    #pragma unroll
    for (int p = 0; p < 2; ++p) {
      const int ldsoff = w * 2048 + p * 1024 + lane * 16;
      const int r = ldsoff >> 7;
      const int Wp = (ldsoff & 127) ^ ((r & 7) << 4);
      gld16(SH + buf * 8192 + ldsoff, ksrc + r * 128 + Wp);
      gld16(SH + 16384 + buf * 8192 + ldsoff, vsrc + (size_t)r * 2048 + Wp);
    }
  };

  union { u32 u[4]; bf16x8 v; } ones;
  ones.u[0] = ones.u[1] = ones.u[2] = ones.u[3] = 0x3f803f80u;  // bf16 1.0 x8

  float mreg = -1e30f;
  f32x4 ls = (f32x4){0.f, 0.f, 0.f, 0.f};
  f32x4 oacc[4];
  #pragma unroll
  for (int ni = 0; ni < 4; ++ni) oacc[ni] = (f32x4){0.f, 0.f, 0.f, 0.f};

  STAGE(0, 0);
  __syncthreads();

  #pragma unroll
  for (int kt = 0; kt < 16; ++kt) {
    const int cur = kt & 1;
    if (kt < 15) STAGE(cur ^ 1, kt + 1);   // flies under QK+SM+PV, drained by barrier

    // ---- S^T = K Q^T: sc[ni][r] = S[kj=ni*16+lg*4+r][qi=lr] ----
    f32x4 sc[4];
    #pragma unroll
    for (int ni = 0; ni < 4; ++ni) sc[ni] = (f32x4){0.f, 0.f, 0.f, 0.f};
    #pragma unroll
    for (int ks = 0; ks < 2; ++ks) {
      bf16x8 kf[4];
      #pragma unroll
      for (int ni = 0; ni < 4; ++ni)
        kf[ni] = *(const bf16x8*)(kp[ks][ni] + cur * 8192);
      __builtin_amdgcn_s_setprio(1);
      #pragma unroll
      for (int ni = 0; ni < 4; ++ni) {
        sc[ni] = mfma16(kf[ni], QBh[ks], sc[ni]);
        sc[ni] = mfma16(kf[ni], QBl[ks], sc[ni]);
      }
      __builtin_amdgcn_s_setprio(0);
    }

    // ---- per-lane online softmax + P store (bf16, packed) ----
    float tm = fmaxf(fmaxf(sc[0][0], sc[0][1]), fmaxf(sc[0][2], sc[0][3]));
    #pragma unroll
    for (int ni = 1; ni < 4; ++ni)
      tm = fmaxf(tm, fmaxf(fmaxf(sc[ni][0], sc[ni][1]), fmaxf(sc[ni][2], sc[ni][3])));
    tm = fmaxf(tm, __shfl_xor(tm, 16));
    tm = fmaxf(tm, __shfl_xor(tm, 32));

    if (!__all(tm <= mreg + 8.0f)) {       // defer-max: P bounded by 2^8
      const float mn = fmaxf(mreg, tm);
      const float alv = exp2f(mreg - mn);
      mreg = mn;
      float alr[4];
      #pragma unroll
      for (int r = 0; r < 4; ++r) alr[r] = __shfl(alv, lg * 4 + r);
      #pragma unroll
      for (int ni = 0; ni < 4; ++ni)
        #pragma unroll
        for (int r = 0; r < 4; ++r) oacc[ni][r] *= alr[r];
      #pragma unroll
      for (int r = 0; r < 4; ++r) ls[r] *= alr[r];
    }

    #pragma unroll
    for (int ni = 0; ni < 4; ++ni) {
      const float p0 = exp2f(sc[ni][0] - mreg);
      const float p1 = exp2f(sc[ni][1] - mreg);
      const float p2 = exp2f(sc[ni][2] - mreg);
      const float p3 = exp2f(sc[ni][3] - mreg);
      *(uint2*)pw[ni] = make_uint2(cvtpk(p0, p1), cvtpk(p2, p3));
    }

    // ---- O += P V ; ls += P @ ones (row-sum on the MFMA pipe) ----
    #pragma unroll
    for (int ks = 0; ks < 2; ++ks) {
      bf16x8 vb[4];
      #pragma unroll
      for (int ni = 0; ni < 4; ++ni)
        vb[ni] = *(const bf16x8*)(kp[ks][ni] + 16384 + cur * 8192);
      const uint2 a = *(const uint2*)pr[ks][0];
      const uint2 b = *(const uint2*)pr[ks][1];
      union { u32 u[4]; bf16x8 v; } pu;
      pu.u[0] = a.x; pu.u[1] = a.y; pu.u[2] = b.x; pu.u[3] = b.y;
      __builtin_amdgcn_s_setprio(1);
      #pragma unroll
      for (int ni = 0; ni < 4; ++ni)
        oacc[ni] = mfma16(pu.v, vb[ni], oacc[ni]);
      ls = mfma16(pu.v, ones.v, ls);
      __builtin_amdgcn_s_setprio(0);
    }

    __syncthreads();   // next tile staged; all waves done with buffers[cur]
  }

  // finalize rows (ls[r] is the complete row-sum, aligned with oacc rows)
  #pragma unroll
  for (int r = 0; r < 4; ++r) {
    const float invr = 1.f / ls[r];
    const int s = s0 + w * 16 + lg * 4 + r;
    #pragma unroll
    for (int ni = 0; ni < 4; ++ni) {
      const int c = hh * HD + ni * 16 + lr;
      const size_t idx = ((size_t)bz * SEQ + s) * CH + c;
      const float v = oacc[ni][r] * invr;
      const u16 hb = f2bf(v);
      av_h[idx] = hb;
      av_l[idx] = f2bf(v - bf2f(hb));
    }
  }
}

extern "C" void kernel_launch(void* const* d_in, const int* in_sizes, int n_in,
                              void* d_out, int out_size, void* d_ws, size_t ws_size,
                              hipStream_t stream) {
  const float* x     = (const float*)d_in[0];  // (8, 512, 32, 32)
  const float* w_qkv = (const float*)d_in[1];  // (1536, 512)
  const float* b_qkv = (const float*)d_in[2];  // (1536,)
  const float* w_o   = (const float*)d_in[3];  // (512, 512)
  const float* b_o   = (const float*)d_in[4];  // (512,)
  float* out = (float*)d_out;                  // (8, 512, 1024) fp32

  char* ws = (char*)d_ws;
  const size_t SZ = (size_t)8 * SEQ * CH * 2;  // one bf16 plane: 8.39 MB
  u16* xt_h = (u16*)(ws + 0 * SZ);             // also avt_h (aliased; xt dead after gemm1)
  u16* xt_l = (u16*)(ws + 1 * SZ);             // also avt_l
  u16* q_h  = (u16*)(ws + 2 * SZ);
  u16* q_l  = (u16*)(ws + 3 * SZ);
  u16* k_h  = (u16*)(ws + 4 * SZ);
  u16* v_h  = (u16*)(ws + 6 * SZ);
  u16* wqkv_h = (u16*)(ws + 7 * SZ);
  u16* wqkv_l = wqkv_h + (size_t)1536 * 512;
  u16* wo_h   = wqkv_l + (size_t)1536 * 512;
  u16* wo_l   = wo_h + (size_t)512 * 512;

  split_both<<<1024, 256, 0, stream>>>(w_qkv, wqkv_h, wqkv_l, w_o, wo_h, wo_l);
  transpose_split<<<dim3(16, 8, 8), 256, 0, stream>>>(x, xt_h, xt_l);

  gemm_hilo<1, 128><<<dim3(8, 12, 8), 256, 0, stream>>>(
      wqkv_h, wqkv_l, xt_h, xt_l, b_qkv,
      (void*)q_h, (void*)q_l, (void*)k_h, nullptr, (void*)v_h);

  attn_mfma<<<dim3(1024), 256, 0, stream>>>(
      q_h, q_l, k_h, v_h, xt_h, xt_l);   // avt aliases xt

  gemm_hilo<0, 64><<<dim3(8, 8, 8), 256, 0, stream>>>(
      wo_h, wo_l, xt_h, xt_l, b_o,
      (void*)out, nullptr, nullptr, nullptr, nullptr);
}

// Round 12
// 175.911 us; speedup vs baseline: 1.8173x; 1.0392x over previous
//
#include <hip/hip_runtime.h>
#include <cstddef>
#include <cstdint>

#define CH 512
#define SEQ 1024
#define NH 8
#define HD 64

typedef unsigned short u16;
typedef unsigned int u32;
typedef __attribute__((ext_vector_type(8))) short bf16x8;   // 8 bf16 (4 VGPRs)
typedef __attribute__((ext_vector_type(4))) float f32x4;
typedef __attribute__((ext_vector_type(4))) unsigned short u16x4;

// 0.125 * log2(e): folds the 1/sqrt(64) score scale and exp->exp2 conversion
#define SCLQ 0.1803368801111204f

__device__ __forceinline__ u16 f2bf(float f) {
  unsigned u = __float_as_uint(f);
  u += 0x7fffu + ((u >> 16) & 1u);
  return (u16)(u >> 16);
}
__device__ __forceinline__ float bf2f(u16 h) {
  return __uint_as_float(((unsigned)h) << 16);
}
__device__ __forceinline__ u32 cvtpk(float lo, float hi) {
  u32 r;
  asm("v_cvt_pk_bf16_f32 %0, %1, %2" : "=v"(r) : "v"(lo), "v"(hi));
  return r;
}

__device__ __forceinline__ void gld16(void* lds, const void* g) {
  __builtin_amdgcn_global_load_lds(
      (const __attribute__((address_space(1))) unsigned int*)g,
      (__attribute__((address_space(3))) unsigned int*)lds, 16, 0, 0);
}

__device__ __forceinline__ f32x4 mfma16(bf16x8 a, bf16x8 b, f32x4 c) {
  return __builtin_amdgcn_mfma_f32_16x16x32_bf16(a, b, c, 0, 0, 0);
}

// ---------------- prep: weight hi/lo split + x transpose-split (one dispatch) ----------------
// blocks 0..1023: transpose x (b,512c,1024s) -> xt hi/lo (b,1024s,512c)
// blocks 1024..1791: split w_qkv; blocks 1792..2047: split w_o
__global__ __launch_bounds__(256) void prep(
    const float* __restrict__ x, u16* __restrict__ xh, u16* __restrict__ xl,
    const float* __restrict__ wqkv, u16* __restrict__ wqkv_h, u16* __restrict__ wqkv_l,
    const float* __restrict__ wo, u16* __restrict__ wo_h, u16* __restrict__ wo_l)
{
  __shared__ float tile[64][65];
  const int bid = blockIdx.x;
  const int t = threadIdx.x;
  if (bid < 1024) {
    const int s0 = (bid & 15) * 64, c0 = ((bid >> 4) & 7) * 64, bz = bid >> 7;
    #pragma unroll
    for (int p = 0; p < 16; ++p) {
      int i = p * 256 + t;
      int cl = i >> 6, sl = i & 63;
      tile[cl][sl] = x[((size_t)bz * CH + c0 + cl) * SEQ + s0 + sl];
    }
    __syncthreads();
    #pragma unroll
    for (int p = 0; p < 16; ++p) {
      int i = p * 256 + t;
      int sl = i >> 6, cl = i & 63;
      float v = tile[cl][sl];
      u16 h = f2bf(v);
      size_t idx = ((size_t)bz * SEQ + s0 + sl) * CH + c0 + cl;
      xh[idx] = h;
      xl[idx] = f2bf(v - bf2f(h));
    }
  } else {
    const int b = bid - 1024;
    const float* in; u16* hi; u16* lo; int i;
    if (b < 768) { in = wqkv; hi = wqkv_h; lo = wqkv_l; i = b * 256 + t; }
    else         { in = wo;   hi = wo_h;   lo = wo_l;   i = (b - 768) * 256 + t; }
    float4 v = ((const float4*)in)[i];
    u16x4 h, l;
    h[0] = f2bf(v.x); l[0] = f2bf(v.x - bf2f(h[0]));
    h[1] = f2bf(v.y); l[1] = f2bf(v.y - bf2f(h[1]));
    h[2] = f2bf(v.z); l[2] = f2bf(v.z - bf2f(h[2]));
    h[3] = f2bf(v.w); l[3] = f2bf(v.w - bf2f(h[3]));
    ((u16x4*)hi)[i] = h;
    ((u16x4*)lo)[i] = l;
  }
}

// ---------------- hi/lo split-bf16 GEMM ----------------
// C(bz) = A(MxK=512) * BT(bz, N=1024, K=512)^T + bias ; tile BM x 128
// MODE 0: o0 = fp32 out (b, 512, 1024)
// MODE 1: qkv epilogue -> q_hi,q_lo (pre-scaled), k_hi (no lo), v_hi (transposed)
template<int MODE, int BM>
__global__ __launch_bounds__(256, 2) void gemm_hilo(
    const u16* __restrict__ Ah, const u16* __restrict__ Al,
    const u16* __restrict__ BTh, const u16* __restrict__ BTl,
    const float* __restrict__ bias,
    void* __restrict__ o0, void* __restrict__ o1, void* __restrict__ o2,
    void* __restrict__ o3, void* __restrict__ o4)
{
  constexpr int WM = BM / 2;     // wave M extent
  constexpr int MI = WM / 16;    // m fragments per wave
  const int bx = blockIdx.x, by = blockIdx.y, bz = blockIdx.z;
  const int m0 = by * BM, n0 = bx * 128;
  const char* Ahc = (const char*)Ah;
  const char* Alc = (const char*)Al;
  const char* Bhc = (const char*)BTh + (size_t)bz * SEQ * CH * 2;
  const char* Blc = (const char*)BTl + (size_t)bz * SEQ * CH * 2;

  // rows of 128B: [32 bf16 hi | 32 bf16 lo], XOR-swizzled by (row&7)<<4
  __shared__ __align__(16) u16 As[BM * 64];
  __shared__ __align__(16) u16 Bs[128 * 64];

  const int t = threadIdx.x, w = t >> 6, lane = t & 63;
  const int lr = lane & 15, lg = lane >> 4;
  const int wr = w >> 1, wc = w & 1;

  f32x4 acc[MI][4];
  #pragma unroll
  for (int i = 0; i < MI; ++i)
    #pragma unroll
    for (int j = 0; j < 4; ++j) acc[i][j] = (f32x4){0.f, 0.f, 0.f, 0.f};

  for (int k0 = 0; k0 < CH; k0 += 32) {
    __syncthreads();
    #pragma unroll
    for (int p = 0; p < BM / 32; ++p) {
      const int ldsoff = p * 4096 + w * 1024 + lane * 16;
      const int m = ldsoff >> 7;
      const int W = ldsoff & 127;
      const int Wp = W ^ ((m & 7) << 4);
      const char* src = (Wp < 64 ? Ahc : Alc) + ((size_t)(m0 + m) * CH + k0) * 2 + (Wp & 63);
      gld16((char*)As + p * 4096 + w * 1024, src);
    }
    #pragma unroll
    for (int p = 0; p < 4; ++p) {
      const int ldsoff = p * 4096 + w * 1024 + lane * 16;
      const int n = ldsoff >> 7;
      const int W = ldsoff & 127;
      const int Wp = W ^ ((n & 7) << 4);
      const char* src = (Wp < 64 ? Bhc : Blc) + ((size_t)(n0 + n) * CH + k0) * 2 + (Wp & 63);
      gld16((char*)Bs + p * 4096 + w * 1024, src);
    }
    __syncthreads();

    bf16x8 Afh[MI], Afl[MI], Bfh[4], Bfl[4];
    #pragma unroll
    for (int mi = 0; mi < MI; ++mi) {
      const int m = wr * WM + mi * 16 + lr;
      const int swz = (m & 7) << 4;
      Afh[mi] = *(const bf16x8*)((const char*)As + m * 128 + ((lg * 16) ^ swz));
      Afl[mi] = *(const bf16x8*)((const char*)As + m * 128 + ((64 + lg * 16) ^ swz));
    }
    #pragma unroll
    for (int ni = 0; ni < 4; ++ni) {
      const int n = wc * 64 + ni * 16 + lr;
      const int swz = (n & 7) << 4;
      Bfh[ni] = *(const bf16x8*)((const char*)Bs + n * 128 + ((lg * 16) ^ swz));
      Bfl[ni] = *(const bf16x8*)((const char*)Bs + n * 128 + ((64 + lg * 16) ^ swz));
    }
    #pragma unroll
    for (int mi = 0; mi < MI; ++mi) {
      #pragma unroll
      for (int ni = 0; ni < 4; ++ni) {
        acc[mi][ni] = mfma16(Afh[mi], Bfh[ni], acc[mi][ni]);
        acc[mi][ni] = mfma16(Afh[mi], Bfl[ni], acc[mi][ni]);
        acc[mi][ni] = mfma16(Afl[mi], Bfh[ni], acc[mi][ni]);
      }
    }
  }

  if constexpr (MODE == 0) {
    float* Out = (float*)o0 + (size_t)bz * CH * SEQ;
    #pragma unroll
    for (int mi = 0; mi < MI; ++mi) {
      const int mb = m0 + wr * WM + mi * 16 + lg * 4;
      #pragma unroll
      for (int r = 0; r < 4; ++r) {
        const float bv = bias[mb + r];
        #pragma unroll
        for (int ni = 0; ni < 4; ++ni) {
          const int n = n0 + wc * 64 + ni * 16 + lr;
          Out[(size_t)(mb + r) * SEQ + n] = acc[mi][ni][r] + bv;
        }
      }
    }
  } else {
    u16* qh = (u16*)o0; u16* ql = (u16*)o1;
    u16* kh = (u16*)o2;
    u16* vh = (u16*)o4;
    #pragma unroll
    for (int mi = 0; mi < MI; ++mi) {
      const int mb = m0 + wr * WM + mi * 16 + lg * 4;   // 4 consecutive m rows
      const int sec = mb >> 9;                          // 0=q 1=k 2=v
      const int h = (mb >> 6) & 7;
      const int d = mb & 63;
      const size_t bh = (size_t)bz * NH + h;
      const float b0 = bias[mb + 0], b1 = bias[mb + 1], b2 = bias[mb + 2], b3 = bias[mb + 3];
      #pragma unroll
      for (int ni = 0; ni < 4; ++ni) {
        const int n = n0 + wc * 64 + ni * 16 + lr;      // s
        float c0 = acc[mi][ni][0] + b0;
        float c1 = acc[mi][ni][1] + b1;
        float c2 = acc[mi][ni][2] + b2;
        float c3 = acc[mi][ni][3] + b3;
        if (sec == 2) {
          u16* dst = vh + (bh * HD + d) * SEQ + n;      // v transposed (b,h,d,s)
          dst[0 * SEQ] = f2bf(c0);
          dst[1 * SEQ] = f2bf(c1);
          dst[2 * SEQ] = f2bf(c2);
          dst[3 * SEQ] = f2bf(c3);
        } else if (sec == 1) {                          // k: hi only
          u16* dsth = kh + (bh * SEQ + n) * HD + d;
          u16x4 hv;
          hv[0] = f2bf(c0); hv[1] = f2bf(c1); hv[2] = f2bf(c2); hv[3] = f2bf(c3);
          *(u16x4*)dsth = hv;
        } else {                                        // q: hi/lo, pre-scaled
          c0 *= SCLQ; c1 *= SCLQ; c2 *= SCLQ; c3 *= SCLQ;
          u16* dsth = qh + (bh * SEQ + n) * HD + d;
          u16* dstl = ql + (bh * SEQ + n) * HD + d;
          u16x4 hv, lv;
          hv[0] = f2bf(c0); lv[0] = f2bf(c0 - bf2f(hv[0]));
          hv[1] = f2bf(c1); lv[1] = f2bf(c1 - bf2f(hv[1]));
          hv[2] = f2bf(c2); lv[2] = f2bf(c2 - bf2f(hv[2]));
          hv[3] = f2bf(c3); lv[3] = f2bf(c3 - bf2f(hv[3]));
          *(u16x4*)dsth = hv;
          *(u16x4*)dstl = lv;
        }
      }
    }
  }
}

// ---------------- flash attention: zero-movement P via K-row permutation ----------------
// q: (b,h,1024,64) hi/lo bf16 pre-scaled; k: (b,h,1024,64) hi bf16;
// v: (b,h,64,1024) bf16; out avt: (b,1024,512) hi/lo.
// Swapped QK^T with K rows staged PERMUTED by pi(r)=32(r>>5)+8((r>>2)&3)+4((r>>4)&1)+(r&3):
// then sc[ni][r] = P[pi-permuted kj][q=lr] packs (via cvtpk pairs) DIRECTLY into the
// PV A-fragment for the natural (unpermuted) V — softmax and PV are kj-permutation
// invariant. P never touches LDS. LDS 32KB -> 4 blocks/CU. Row-sum on the MFMA pipe.
__global__ __launch_bounds__(256, 4) void attn_mfma(
    const u16* __restrict__ q_h, const u16* __restrict__ q_l,
    const u16* __restrict__ k_h, const u16* __restrict__ v_h,
    u16* __restrict__ av_h, u16* __restrict__ av_l)
{
  // XCD swizzle: all 16 q-tiles of one (b,h) land on one XCD (bid%8)
  const int bid = blockIdx.x;
  const int xcd = bid & 7, rr = bid >> 3;      // rr 0..127
  const int qt = rr & 15, ghi = rr >> 4;       // ghi 0..7
  const int g = ghi * 8 + xcd;                 // (b,h) group 0..63
  const int hh = g & 7, bz = g >> 3;
  const int bhead = bz * NH + hh;
  const int s0 = qt * 64;
  const int t = threadIdx.x, w = t >> 6, lane = t & 63;
  const int lr = lane & 15, lg = lane >> 4;

  // LDS (32KB): K buf0 @0, K buf1 @8192 (rows pi-permuted), V buf0 @16384, V buf1 @24576
  __shared__ __align__(16) char SH[32768];

  // Q fragments: wave w owns q-rows s0 + w*16 .. +16
  bf16x8 QBh[2], QBl[2];
  {
    const size_t qrow = (size_t)bhead * SEQ + s0 + w * 16 + lr;
    #pragma unroll
    for (int ks = 0; ks < 2; ++ks) {
      QBh[ks] = *(const bf16x8*)((const char*)q_h + qrow * 128 + ks * 64 + lg * 16);
      QBl[ks] = *(const bf16x8*)((const char*)q_l + qrow * 128 + ks * 64 + lg * 16);
    }
  }

  const char* Khb = (const char*)k_h + (size_t)bhead * SEQ * 128;
  const char* Vbb = (const char*)v_h + (size_t)bhead * HD * 2048;

  // hoisted LDS read pointers (K; V at +16384 with the same row/offset formula)
  const char* kp[2][4];
  #pragma unroll
  for (int ks = 0; ks < 2; ++ks)
    #pragma unroll
    for (int ni = 0; ni < 4; ++ni) {
      const int row = ni * 16 + lr;
      kp[ks][ni] = SH + row * 128 + ((ks * 64 + lg * 16) ^ ((row & 7) << 4));
    }

  // stage K tile (8KB, rows permuted by pi) + V tile (8KB, natural rows);
  // linear LDS dest, pre-swizzled source (rule #21).
  auto STAGE = [&](int buf, int tile) {
    const char* ksrc = Khb + (size_t)tile * 8192;
    const char* vsrc = Vbb + (size_t)tile * 128;
    #pragma unroll
    for (int p = 0; p < 2; ++p) {
      const int ldsoff = w * 2048 + p * 1024 + lane * 16;
      const int r = ldsoff >> 7;
      const int pr_ = ((r >> 5) << 5) | (((r >> 2) & 3) << 3) | (((r >> 4) & 1) << 2) | (r & 3);
      const int Wp = (ldsoff & 127) ^ ((r & 7) << 4);
      gld16(SH + buf * 8192 + ldsoff, ksrc + pr_ * 128 + Wp);
      gld16(SH + 16384 + buf * 8192 + ldsoff, vsrc + (size_t)r * 2048 + Wp);
    }
  };

  union { u32 u[4]; bf16x8 v; } ones;
  ones.u[0] = ones.u[1] = ones.u[2] = ones.u[3] = 0x3f803f80u;  // bf16 1.0 x8

  float mreg = -1e30f;
  f32x4 ls = (f32x4){0.f, 0.f, 0.f, 0.f};
  f32x4 oacc[4];
  #pragma unroll
  for (int ni = 0; ni < 4; ++ni) oacc[ni] = (f32x4){0.f, 0.f, 0.f, 0.f};

  STAGE(0, 0);
  __syncthreads();

  #pragma unroll
  for (int kt = 0; kt < 16; ++kt) {
    const int cur = kt & 1;
    if (kt < 15) STAGE(cur ^ 1, kt + 1);   // flies under QK+SM+PV, drained by barrier

    // ---- S^T = K Q^T: sc[ni][r] = S[pi(16ni+4lg+r)][qi=lr] ----
    f32x4 sc[4];
    #pragma unroll
    for (int ni = 0; ni < 4; ++ni) sc[ni] = (f32x4){0.f, 0.f, 0.f, 0.f};
    #pragma unroll
    for (int ks = 0; ks < 2; ++ks) {
      bf16x8 kf[4];
      #pragma unroll
      for (int ni = 0; ni < 4; ++ni)
        kf[ni] = *(const bf16x8*)(kp[ks][ni] + cur * 8192);
      __builtin_amdgcn_s_setprio(1);
      #pragma unroll
      for (int ni = 0; ni < 4; ++ni) {
        sc[ni] = mfma16(kf[ni], QBh[ks], sc[ni]);
        sc[ni] = mfma16(kf[ni], QBl[ks], sc[ni]);
      }
      __builtin_amdgcn_s_setprio(0);
    }

    // ---- per-lane online softmax (permutation-invariant) ----
    float tm = fmaxf(fmaxf(sc[0][0], sc[0][1]), fmaxf(sc[0][2], sc[0][3]));
    #pragma unroll
    for (int ni = 1; ni < 4; ++ni)
      tm = fmaxf(tm, fmaxf(fmaxf(sc[ni][0], sc[ni][1]), fmaxf(sc[ni][2], sc[ni][3])));
    tm = fmaxf(tm, __shfl_xor(tm, 16));
    tm = fmaxf(tm, __shfl_xor(tm, 32));

    if (!__all(tm <= mreg + 8.0f)) {       // defer-max: P bounded by 2^8
      const float mn = fmaxf(mreg, tm);
      const float alv = exp2f(mreg - mn);
      mreg = mn;
      float alr[4];
      #pragma unroll
      for (int r = 0; r < 4; ++r) alr[r] = __shfl(alv, lg * 4 + r);
      #pragma unroll
      for (int ni = 0; ni < 4; ++ni)
        #pragma unroll
        for (int r = 0; r < 4; ++r) oacc[ni][r] *= alr[r];
      #pragma unroll
      for (int r = 0; r < 4; ++r) ls[r] *= alr[r];
    }

    // ---- P = exp2(S - m), packed in-register: pk[ni] = PV A-frag words ----
    u32 pk0[4], pk1[4];
    #pragma unroll
    for (int ni = 0; ni < 4; ++ni) {
      const float p0 = exp2f(sc[ni][0] - mreg);
      const float p1 = exp2f(sc[ni][1] - mreg);
      const float p2 = exp2f(sc[ni][2] - mreg);
      const float p3 = exp2f(sc[ni][3] - mreg);
      pk0[ni] = cvtpk(p0, p1);
      pk1[ni] = cvtpk(p2, p3);
    }

    // ---- O += P V ; ls += P @ ones  (A-operand straight from registers) ----
    #pragma unroll
    for (int ks = 0; ks < 2; ++ks) {
      union { u32 u[4]; bf16x8 v; } pa;
      pa.u[0] = pk0[2 * ks];     pa.u[1] = pk1[2 * ks];
      pa.u[2] = pk0[2 * ks + 1]; pa.u[3] = pk1[2 * ks + 1];
      bf16x8 vb[4];
      #pragma unroll
      for (int ni = 0; ni < 4; ++ni)
        vb[ni] = *(const bf16x8*)(kp[ks][ni] + 16384 + cur * 8192);
      __builtin_amdgcn_s_setprio(1);
      #pragma unroll
      for (int ni = 0; ni < 4; ++ni)
        oacc[ni] = mfma16(pa.v, vb[ni], oacc[ni]);
      ls = mfma16(pa.v, ones.v, ls);
      __builtin_amdgcn_s_setprio(0);
    }

    __syncthreads();   // next tile staged; all waves done with buffers[cur]
  }

  // finalize rows (ls[r] is the complete row-sum, aligned with oacc rows)
  #pragma unroll
  for (int r = 0; r < 4; ++r) {
    const float invr = 1.f / ls[r];
    const int s = s0 + w * 16 + lg * 4 + r;
    #pragma unroll
    for (int ni = 0; ni < 4; ++ni) {
      const int c = hh * HD + ni * 16 + lr;
      const size_t idx = ((size_t)bz * SEQ + s) * CH + c;
      const float v = oacc[ni][r] * invr;
      const u16 hb = f2bf(v);
      av_h[idx] = hb;
      av_l[idx] = f2bf(v - bf2f(hb));
    }
  }
}

extern "C" void kernel_launch(void* const* d_in, const int* in_sizes, int n_in,
                              void* d_out, int out_size, void* d_ws, size_t ws_size,
                              hipStream_t stream) {
  const float* x     = (const float*)d_in[0];  // (8, 512, 32, 32)
  const float* w_qkv = (const float*)d_in[1];  // (1536, 512)
  const float* b_qkv = (const float*)d_in[2];  // (1536,)
  const float* w_o   = (const float*)d_in[3];  // (512, 512)
  const float* b_o   = (const float*)d_in[4];  // (512,)
  float* out = (float*)d_out;                  // (8, 512, 1024) fp32

  char* ws = (char*)d_ws;
  const size_t SZ = (size_t)8 * SEQ * CH * 2;  // one bf16 plane: 8.39 MB
  u16* xt_h = (u16*)(ws + 0 * SZ);             // also avt_h (aliased; xt dead after gemm1)
  u16* xt_l = (u16*)(ws + 1 * SZ);             // also avt_l
  u16* q_h  = (u16*)(ws + 2 * SZ);
  u16* q_l  = (u16*)(ws + 3 * SZ);
  u16* k_h  = (u16*)(ws + 4 * SZ);
  u16* v_h  = (u16*)(ws + 6 * SZ);
  u16* wqkv_h = (u16*)(ws + 7 * SZ);
  u16* wqkv_l = wqkv_h + (size_t)1536 * 512;
  u16* wo_h   = wqkv_l + (size_t)1536 * 512;
  u16* wo_l   = wo_h + (size_t)512 * 512;

  prep<<<2048, 256, 0, stream>>>(x, xt_h, xt_l, w_qkv, wqkv_h, wqkv_l, w_o, wo_h, wo_l);

  gemm_hilo<1, 128><<<dim3(8, 12, 8), 256, 0, stream>>>(
      wqkv_h, wqkv_l, xt_h, xt_l, b_qkv,
      (void*)q_h, (void*)q_l, (void*)k_h, nullptr, (void*)v_h);

  attn_mfma<<<dim3(1024), 256, 0, stream>>>(
      q_h, q_l, k_h, v_h, xt_h, xt_l);   // avt aliases xt

  gemm_hilo<0, 64><<<dim3(8, 8, 8), 256, 0, stream>>>(
      wo_h, wo_l, xt_h, xt_l, b_o,
      (void*)out, nullptr, nullptr, nullptr, nullptr);
}